// Round 2
// baseline (4006.429 us; speedup 1.0000x reference)
//
#include <hip/hip_runtime.h>

typedef unsigned short u16;
typedef short short8 __attribute__((ext_vector_type(8)));
typedef float f32x4 __attribute__((ext_vector_type(4)));
typedef unsigned short u16x4 __attribute__((ext_vector_type(4)));

typedef short8 short8_a __attribute__((may_alias));
typedef f32x4 f32x4_a __attribute__((may_alias));
typedef u16x4 u16x4_a __attribute__((may_alias));
typedef unsigned int uint_a __attribute__((may_alias));

__device__ __forceinline__ u16 f2b(float f) {
  unsigned u = __float_as_uint(f);
  u += 0x7FFFu + ((u >> 16) & 1u);
  return (u16)(u >> 16);
}

__device__ __forceinline__ void mfma_b(f32x4& d, short8 a, short8 b) {
  asm("v_mfma_f32_16x16x32_bf16 %0, %1, %2, %0" : "+v"(d) : "v"(a), "v"(b));
}

__device__ __forceinline__ void gload16(const void* g, void* l) {
  __builtin_amdgcn_global_load_lds((__attribute__((address_space(1))) void*)(g),
                                   (__attribute__((address_space(3))) void*)(l),
                                   16, 0, 0);
}

// ---------------- fp32 -> bf16 cast ----------------
__global__ __launch_bounds__(256) void k_cast(const float* __restrict__ in,
                                              u16* __restrict__ out, int n4) {
  int i = blockIdx.x * 256 + threadIdx.x;
  if (i >= n4) return;
  f32x4 v = ((const f32x4_a*)in)[i];
  u16x4 o;
  o[0] = f2b(v[0]); o[1] = f2b(v[1]); o[2] = f2b(v[2]); o[3] = f2b(v[3]);
  ((u16x4_a*)out)[i] = o;
}

// ---------------- rope cos/sin table: [2048 s][64 j] ----------------
__global__ __launch_bounds__(256) void k_tab(float* __restrict__ cost,
                                             float* __restrict__ sint) {
  int i = blockIdx.x * 256 + threadIdx.x;  // 131072 total
  int s = i >> 6, j = i & 63;
  float freq = powf(500000.0f, -(float)j * (1.0f / 64.0f));
  float a = (float)s * freq;
  float sv, cv;
  sincosf(a, &sv, &cv);
  cost[i] = cv;
  sint[i] = sv;
}

// ---------------- RoPE + cast fp32->bf16 (interleaved pairs) ----------------
__global__ __launch_bounds__(256) void k_rope(const float* __restrict__ in, int ld_in,
                                              u16* __restrict__ out, int ncols,
                                              const float* __restrict__ cost,
                                              const float* __restrict__ sint,
                                              float scale, int total4) {
  int i = blockIdx.x * 256 + threadIdx.x;
  if (i >= total4) return;
  int base = i * 4;
  int s = base / ncols;
  int col = base - s * ncols;
  int j0 = (col & 127) >> 1;
  f32x4 v = *(const f32x4_a*)(in + (long)s * ld_in + col);
  int tb = (s << 6) + j0;
  float c0 = cost[tb], s0 = sint[tb];
  float c1 = cost[tb + 1], s1 = sint[tb + 1];
  u16x4 o;
  o[0] = f2b((v[0] * c0 - v[1] * s0) * scale);
  o[1] = f2b((v[0] * s0 + v[1] * c0) * scale);
  o[2] = f2b((v[2] * c1 - v[3] * s1) * scale);
  o[3] = f2b((v[2] * s1 + v[3] * c1) * scale);
  *(u16x4_a*)(out + (long)s * ncols + col) = o;
}

// ---------------- bf16 GEMM: C[M][N] = A[M][K] * B[N][K]^T (m97 structure) --------
__global__ __launch_bounds__(256, 2)
void k_gemm(const u16* __restrict__ A, const u16* __restrict__ B,
            float* __restrict__ C, int M, int N, int K) {
  __shared__ u16 As[4096];  // 128 rows x 32 k
  __shared__ u16 Bs[4096];
  const int tid = threadIdx.x;
  const int w = tid >> 6, lane = tid & 63;
  const int hi = lane >> 4, lo = lane & 15;
  const int nwg = gridDim.x;
  int bid = blockIdx.x;
  if ((nwg & 7) == 0) bid = (bid & 7) * (nwg >> 3) + (bid >> 3);  // XCD swizzle
  const int ntn = N >> 7;
  const int tm = bid / ntn, tn = bid - tm * ntn;
  const int m0 = tm << 7, n0 = tn << 7;
  const int wr = w >> 1, wc = w & 1;

  const int e0 = w * 512 + lane * 8;  // elem offset this lane stages (round 0)
  const int e1 = e0 + 2048;
  const u16* Ag0 = A + (long)(m0 + (e0 >> 5)) * K + (e0 & 31);
  const u16* Ag1 = A + (long)(m0 + (e1 >> 5)) * K + (e1 & 31);
  const u16* Bg0 = B + (long)(n0 + (e0 >> 5)) * K + (e0 & 31);
  const u16* Bg1 = B + (long)(n0 + (e1 >> 5)) * K + (e1 & 31);
  u16* As0 = As + w * 512;
  u16* As1 = As0 + 2048;
  u16* Bs0 = Bs + w * 512;
  u16* Bs1 = Bs0 + 2048;

  f32x4 acc[4][4] = {};
  const int aoff = (wr * 64 + lo) * 32 + hi * 8;
  const int boff = (wc * 64 + lo) * 32 + hi * 8;

  for (int k0 = 0; k0 < K; k0 += 32) {
    __syncthreads();
    gload16(Ag0 + k0, As0);
    gload16(Ag1 + k0, As1);
    gload16(Bg0 + k0, Bs0);
    gload16(Bg1 + k0, Bs1);
    __syncthreads();
    short8 af[4], bf[4];
#pragma unroll
    for (int m = 0; m < 4; ++m) af[m] = *(const short8_a*)(As + aoff + m * 512);
#pragma unroll
    for (int n = 0; n < 4; ++n) bf[n] = *(const short8_a*)(Bs + boff + n * 512);
#pragma unroll
    for (int m = 0; m < 4; ++m)
#pragma unroll
      for (int n = 0; n < 4; ++n) mfma_b(acc[m][n], af[m], bf[n]);
  }

#pragma unroll
  for (int m = 0; m < 4; ++m) {
    const int row0 = m0 + wr * 64 + m * 16 + hi * 4;
#pragma unroll
    for (int n = 0; n < 4; ++n) {
      const int col = n0 + wc * 64 + n * 16 + lo;
#pragma unroll
      for (int r = 0; r < 4; ++r)
        C[(long)(row0 + r) * N + col] = acc[m][n][r];
    }
  }
}

// ---------------- BISECT: brute-force exact attention ----------------
// One wave per (q, h). Scores: lane-parallel over keys, fp32 dot of bf16 Q,K.
// PV: d-parallel (2 d per lane), fp32 V read directly from KVf (no transpose).
__global__ __launch_bounds__(256)
void k_attn_ref(const u16* __restrict__ Qb, const u16* __restrict__ Kb,
                const float* __restrict__ KVf, u16* __restrict__ Ab) {
  const int tid = threadIdx.x;
  const int w = tid >> 6, lane = tid & 63;
  const long idx = (long)blockIdx.x * 4 + w;  // 65536 = 2048 q * 32 h
  const int q = (int)(idx >> 5);
  const int h = (int)(idx & 31);
  const int hkv = h >> 2;
  __shared__ float Qs[4][128];
  {
    unsigned v = *(const uint_a*)(Qb + (long)q * 4096 + h * 128 + lane * 2);
    Qs[w][lane * 2] = __uint_as_float(v << 16);
    Qs[w][lane * 2 + 1] = __uint_as_float(v & 0xFFFF0000u);
  }
  __syncthreads();
  float o0 = 0.f, o1 = 0.f, m = -1e30f, l = 0.f;
  const int d0 = lane * 2, d1 = d0 + 1;
  const float* Vbase = KVf + 1024 + hkv * 128;  // V[k][d] = Vbase[k*2048 + d]
  for (int kv0 = 0; kv0 <= q; kv0 += 64) {
    const int key = kv0 + lane;
    float s = -1e30f;
    if (key <= q) {
      const u16* krow = Kb + (long)key * 1024 + hkv * 128;
      float acc = 0.f;
#pragma unroll
      for (int i = 0; i < 16; ++i) {
        short8 kk = *(const short8_a*)(krow + i * 8);
#pragma unroll
        for (int e = 0; e < 8; ++e) {
          unsigned ku = ((unsigned)(u16)kk[e]) << 16;
          acc += Qs[w][i * 8 + e] * __uint_as_float(ku);
        }
      }
      s = acc;
    }
    float cm = s;
#pragma unroll
    for (int off = 1; off < 64; off <<= 1) cm = fmaxf(cm, __shfl_xor(cm, off));
    const float m_new = fmaxf(m, cm);
    const float scale = __expf(m - m_new);
    const float p = (key <= q) ? __expf(s - m_new) : 0.f;
    float cs = p;
#pragma unroll
    for (int off = 1; off < 64; off <<= 1) cs += __shfl_xor(cs, off);
    l = l * scale + cs;
    o0 *= scale;
    o1 *= scale;
    const int nk = min(64, q - kv0 + 1);
    for (int j = 0; j < nk; ++j) {
      const float pj = __shfl(p, j);
      const float* vr = Vbase + (long)(kv0 + j) * 2048;
      o0 += pj * vr[d0];
      o1 += pj * vr[d1];
    }
    m = m_new;
  }
  const float inv = 1.0f / l;
  Ab[(long)q * 4096 + h * 128 + d0] = f2b(o0 * inv);
  Ab[(long)q * 4096 + h * 128 + d1] = f2b(o1 * inv);
}

// ---------------- host ----------------
extern "C" void kernel_launch(void* const* d_in, const int* in_sizes, int n_in,
                              void* d_out, int out_size, void* d_ws, size_t ws_size,
                              hipStream_t stream) {
  const float* x = (const float*)d_in[0];
  const float* wq = (const float*)d_in[1];
  const float* wk = (const float*)d_in[2];
  const float* wv = (const float*)d_in[3];
  const float* wo = (const float*)d_in[4];
  float* out = (float*)d_out;
  char* ws = (char*)d_ws;

  size_t off = 0;
  u16* xb = (u16*)(ws + off); off += 16777216;       // 2048x4096 bf16
  u16* wqb = (u16*)(ws + off); off += 33554432;      // 4096x4096 bf16
  u16* wkvb = (u16*)(ws + off); off += 16777216;     // [wk;wv] 2048x4096 bf16
  u16* wob = (u16*)(ws + off); off += 33554432;      // 4096x4096 bf16
  float* Qf = (float*)(ws + off); off += 33554432;   // 2048x4096 f32
  float* KVf = (float*)(ws + off); off += 16777216;  // 2048x2048 f32
  u16* Qb = (u16*)(ws + off); off += 16777216;       // 2048x4096 bf16
  u16* Kb = (u16*)(ws + off); off += 4194304;        // 2048x1024 bf16
  u16* Vtb = (u16*)(ws + off); off += 4194304;       // 1024x2048 bf16 (unused this round)
  float* cost = (float*)(ws + off); off += 524288;   // 2048x64 f32
  float* sint = (float*)(ws + off); off += 524288;
  u16* Ab = (u16*)Qf;  // reuse Qf region (dead after RoPE)
  (void)Vtb;

  // casts
  k_cast<<<8192, 256, 0, stream>>>(x, xb, 2097152);
  k_cast<<<16384, 256, 0, stream>>>(wq, wqb, 4194304);
  k_cast<<<4096, 256, 0, stream>>>(wk, wkvb, 1048576);
  k_cast<<<4096, 256, 0, stream>>>(wv, wkvb + 4194304, 1048576);
  k_cast<<<16384, 256, 0, stream>>>(wo, wob, 4194304);
  k_tab<<<512, 256, 0, stream>>>(cost, sint);

  // projections
  k_gemm<<<512, 256, 0, stream>>>(xb, wqb, Qf, 2048, 4096, 4096);
  k_gemm<<<256, 256, 0, stream>>>(xb, wkvb, KVf, 2048, 2048, 4096);

  // rope + casts (scale 1/sqrt(128) folded into Q)
  k_rope<<<8192, 256, 0, stream>>>(Qf, 4096, Qb, 4096, cost, sint,
                                   0.08838834764831845f, 2097152);
  k_rope<<<2048, 256, 0, stream>>>(KVf, 2048, Kb, 1024, cost, sint, 1.0f, 524288);

  // attention (brute-force bisect version)
  k_attn_ref<<<16384, 256, 0, stream>>>(Qb, Kb, KVf, Ab);

  // output projection
  k_gemm<<<512, 256, 0, stream>>>(Ab, wob, out, 2048, 4096, 4096);
}

// Round 4
// 622.951 us; speedup vs baseline: 6.4314x; 6.4314x over previous
//
#include <hip/hip_runtime.h>

typedef unsigned short u16;
typedef short short8 __attribute__((ext_vector_type(8)));
typedef float f32x4 __attribute__((ext_vector_type(4)));
typedef unsigned short u16x4 __attribute__((ext_vector_type(4)));

typedef short8 short8_a __attribute__((may_alias));
typedef f32x4 f32x4_a __attribute__((may_alias));
typedef u16x4 u16x4_a __attribute__((may_alias));
typedef unsigned int uint_a __attribute__((may_alias));

__device__ __forceinline__ u16 f2b(float f) {
  unsigned u = __float_as_uint(f);
  u += 0x7FFFu + ((u >> 16) & 1u);
  return (u16)(u >> 16);
}

// Verified-context MFMA (GEMM: results read far from issue; passed R2 validation)
__device__ __forceinline__ void mfma_b(f32x4& d, short8 a, short8 b) {
  asm("v_mfma_f32_16x16x32_bf16 %0, %1, %2, %0" : "+v"(d) : "v"(a), "v"(b));
}

// Hazard-guarded MFMA for contexts where D is read by VALU soon after issue.
// The compiler's hazard recognizer can't see inside asm; s_nop 7 x2 covers the
// max MFMA-write -> VALU-read wait-state requirement.
__device__ __forceinline__ void mfma_s(f32x4& d, short8 a, short8 b) {
  asm("v_mfma_f32_16x16x32_bf16 %0, %1, %2, %0\n\t"
      "s_nop 7\n\t"
      "s_nop 7"
      : "+v"(d) : "v"(a), "v"(b));
}

__device__ __forceinline__ void gload16(const void* g, void* l) {
  __builtin_amdgcn_global_load_lds((__attribute__((address_space(1))) void*)(g),
                                   (__attribute__((address_space(3))) void*)(l),
                                   16, 0, 0);
}

// ---------------- fp32 -> bf16 cast ----------------
__global__ __launch_bounds__(256) void k_cast(const float* __restrict__ in,
                                              u16* __restrict__ out, int n4) {
  int i = blockIdx.x * 256 + threadIdx.x;
  if (i >= n4) return;
  f32x4 v = ((const f32x4_a*)in)[i];
  u16x4 o;
  o[0] = f2b(v[0]); o[1] = f2b(v[1]); o[2] = f2b(v[2]); o[3] = f2b(v[3]);
  ((u16x4_a*)out)[i] = o;
}

// ---------------- rope cos/sin table: [2048 s][64 j] ----------------
__global__ __launch_bounds__(256) void k_tab(float* __restrict__ cost,
                                             float* __restrict__ sint) {
  int i = blockIdx.x * 256 + threadIdx.x;  // 131072 total
  int s = i >> 6, j = i & 63;
  float freq = powf(500000.0f, -(float)j * (1.0f / 64.0f));
  float a = (float)s * freq;
  float sv, cv;
  sincosf(a, &sv, &cv);
  cost[i] = cv;
  sint[i] = sv;
}

// ---------------- RoPE + cast fp32->bf16 (interleaved pairs) ----------------
__global__ __launch_bounds__(256) void k_rope(const float* __restrict__ in, int ld_in,
                                              u16* __restrict__ out, int ncols,
                                              const float* __restrict__ cost,
                                              const float* __restrict__ sint,
                                              float scale, int total4) {
  int i = blockIdx.x * 256 + threadIdx.x;
  if (i >= total4) return;
  int base = i * 4;
  int s = base / ncols;
  int col = base - s * ncols;
  int j0 = (col & 127) >> 1;
  f32x4 v = *(const f32x4_a*)(in + (long)s * ld_in + col);
  int tb = (s << 6) + j0;
  float c0 = cost[tb], s0 = sint[tb];
  float c1 = cost[tb + 1], s1 = sint[tb + 1];
  u16x4 o;
  o[0] = f2b((v[0] * c0 - v[1] * s0) * scale);
  o[1] = f2b((v[0] * s0 + v[1] * c0) * scale);
  o[2] = f2b((v[2] * c1 - v[3] * s1) * scale);
  o[3] = f2b((v[2] * s1 + v[3] * c1) * scale);
  *(u16x4_a*)(out + (long)s * ncols + col) = o;
}

// ---------------- transpose + cast: V [2048 s][1024 c] -> [1024 c][2048 s] bf16 ----
__global__ __launch_bounds__(256) void k_transpose(const float* __restrict__ in, int ld,
                                                   u16* __restrict__ out, int out_ld) {
  __shared__ float tile[32][33];
  int tx = threadIdx.x & 31, ty = threadIdx.x >> 5;  // ty 0..7
  int sb = blockIdx.x & 63, cb = blockIdx.x >> 6;
  int s0 = sb << 5, c0 = cb << 5;
#pragma unroll
  for (int r = 0; r < 4; ++r)
    tile[ty + r * 8][tx] = in[(long)(s0 + ty + r * 8) * ld + c0 + tx];
  __syncthreads();
#pragma unroll
  for (int r = 0; r < 4; ++r)
    out[(long)(c0 + ty + r * 8) * out_ld + s0 + tx] = f2b(tile[tx][ty + r * 8]);
}

// ---------------- bf16 GEMM: C[M][N] = A[M][K] * B[N][K]^T (m97 structure) --------
__global__ __launch_bounds__(256, 2)
void k_gemm(const u16* __restrict__ A, const u16* __restrict__ B,
            float* __restrict__ C, int M, int N, int K) {
  __shared__ u16 As[4096];  // 128 rows x 32 k
  __shared__ u16 Bs[4096];
  const int tid = threadIdx.x;
  const int w = tid >> 6, lane = tid & 63;
  const int hi = lane >> 4, lo = lane & 15;
  const int nwg = gridDim.x;
  int bid = blockIdx.x;
  if ((nwg & 7) == 0) bid = (bid & 7) * (nwg >> 3) + (bid >> 3);  // XCD swizzle
  const int ntn = N >> 7;
  const int tm = bid / ntn, tn = bid - tm * ntn;
  const int m0 = tm << 7, n0 = tn << 7;
  const int wr = w >> 1, wc = w & 1;

  const int e0 = w * 512 + lane * 8;  // elem offset this lane stages (round 0)
  const int e1 = e0 + 2048;
  const u16* Ag0 = A + (long)(m0 + (e0 >> 5)) * K + (e0 & 31);
  const u16* Ag1 = A + (long)(m0 + (e1 >> 5)) * K + (e1 & 31);
  const u16* Bg0 = B + (long)(n0 + (e0 >> 5)) * K + (e0 & 31);
  const u16* Bg1 = B + (long)(n0 + (e1 >> 5)) * K + (e1 & 31);
  u16* As0 = As + w * 512;
  u16* As1 = As0 + 2048;
  u16* Bs0 = Bs + w * 512;
  u16* Bs1 = Bs0 + 2048;

  f32x4 acc[4][4] = {};
  const int aoff = (wr * 64 + lo) * 32 + hi * 8;
  const int boff = (wc * 64 + lo) * 32 + hi * 8;

  for (int k0 = 0; k0 < K; k0 += 32) {
    __syncthreads();
    gload16(Ag0 + k0, As0);
    gload16(Ag1 + k0, As1);
    gload16(Bg0 + k0, Bs0);
    gload16(Bg1 + k0, Bs1);
    __syncthreads();
    short8 af[4], bf[4];
#pragma unroll
    for (int m = 0; m < 4; ++m) af[m] = *(const short8_a*)(As + aoff + m * 512);
#pragma unroll
    for (int n = 0; n < 4; ++n) bf[n] = *(const short8_a*)(Bs + boff + n * 512);
#pragma unroll
    for (int m = 0; m < 4; ++m)
#pragma unroll
      for (int n = 0; n < 4; ++n) mfma_b(acc[m][n], af[m], bf[n]);
  }

#pragma unroll
  for (int m = 0; m < 4; ++m) {
    const int row0 = m0 + wr * 64 + m * 16 + hi * 4;
#pragma unroll
    for (int n = 0; n < 4; ++n) {
      const int col = n0 + wc * 64 + n * 16 + lo;
#pragma unroll
      for (int r = 0; r < 4; ++r)
        C[(long)(row0 + r) * N + col] = acc[m][n][r];
    }
  }
}

// ---------------- causal GQA flash attention (MFMA, hazard-guarded) ----------------
// Qb: [2048][4096] bf16 (pre-scaled by 1/sqrt(128)), Kb: [2048][1024] bf16,
// Vt: [1024][2048] bf16 (d-major), Ab out: [2048][4096] bf16.
#define KLD 136  // 128 + 8 pad (elems)
#define VLD 72   // 64 + 8 pad (elems)
__global__ __launch_bounds__(256, 2)
void k_attn(const u16* __restrict__ Qb, const u16* __restrict__ Kb,
            const u16* __restrict__ Vt, u16* __restrict__ Ab) {
  __shared__ u16 Ks[64 * KLD];
  __shared__ u16 Vs[128 * VLD];
  __shared__ u16 Ps[4 * 16 * VLD];

  const int tid = threadIdx.x;
  const int w = tid >> 6, lane = tid & 63;
  const int hi = lane >> 4, lo = lane & 15;
  const int h = blockIdx.x >> 5;
  const int qt = blockIdx.x & 31;
  const int hkv = h >> 2;
  const int q0 = qt * 64;
  const int qrow = q0 + w * 16 + lo;  // score-q for this lane (D col = lo)

  short8 qf[4];
#pragma unroll
  for (int c = 0; c < 4; ++c)
    qf[c] = *(const short8_a*)(Qb + (long)qrow * 4096 + h * 128 + c * 32 + hi * 8);

  f32x4 o[8] = {};
  float m_run = -1e30f, l_run = 0.f;
  u16* Pw = Ps + w * (16 * VLD);

  const int ntiles = qt + 1;
  for (int t = 0; t < ntiles; ++t) {
    const int kv0 = t * 64;
    __syncthreads();
    // stage K tile [64][128] -> padded LDS
#pragma unroll
    for (int r = 0; r < 4; ++r) {
      int i = r * 256 + tid;
      int key = i >> 4, d8 = (i & 15) * 8;
      short8 v = *(const short8_a*)(Kb + (long)(kv0 + key) * 1024 + hkv * 128 + d8);
      *(short8_a*)(Ks + key * KLD + d8) = v;
    }
    // stage V^T tile [128][64] -> padded LDS
#pragma unroll
    for (int r = 0; r < 4; ++r) {
      int i = r * 256 + tid;
      int dd = i >> 3, k8 = (i & 7) * 8;
      short8 v = *(const short8_a*)(Vt + (long)hkv * 262144 + (long)dd * 2048 + kv0 + k8);
      *(short8_a*)(Vs + dd * VLD + k8) = v;
    }
    __syncthreads();

    // swapped QK^T: D[key = hi*4+r (+16*kt)][q = lo]
    f32x4 sc[4] = {};
#pragma unroll
    for (int c = 0; c < 4; ++c) {
#pragma unroll
      for (int kt = 0; kt < 4; ++kt) {
        short8 kf = *(const short8_a*)(Ks + (kt * 16 + lo) * KLD + c * 32 + hi * 8);
        mfma_s(sc[kt], kf, qf[c]);
      }
    }
    if (t == ntiles - 1) {  // diagonal tile: causal mask
#pragma unroll
      for (int kt = 0; kt < 4; ++kt)
#pragma unroll
        for (int r = 0; r < 4; ++r) {
          int key = kv0 + kt * 16 + hi * 4 + r;
          if (key > qrow) sc[kt][r] = -1e30f;
        }
    }
    // online softmax (row q = lo; lanes hi=0..3 hold 16 keys each)
    float tmax = -1e30f;
#pragma unroll
    for (int kt = 0; kt < 4; ++kt)
#pragma unroll
      for (int r = 0; r < 4; ++r) tmax = fmaxf(tmax, sc[kt][r]);
    tmax = fmaxf(tmax, __shfl_xor(tmax, 16));
    tmax = fmaxf(tmax, __shfl_xor(tmax, 32));
    float m_new = fmaxf(m_run, tmax);
    float scale = __expf(m_run - m_new);
    float psum = 0.f;
    float p[16];
#pragma unroll
    for (int kt = 0; kt < 4; ++kt)
#pragma unroll
      for (int r = 0; r < 4; ++r) {
        float pv = __expf(sc[kt][r] - m_new);
        p[kt * 4 + r] = pv;
        psum += pv;
      }
    psum += __shfl_xor(psum, 16);
    psum += __shfl_xor(psum, 32);
    l_run = l_run * scale + psum;
    m_run = m_new;
    // rescale O (PV-D rows q = hi*4+r need the scale of score-lane lo = hi*4+r)
    float srow[4];
#pragma unroll
    for (int r = 0; r < 4; ++r) srow[r] = __shfl(scale, hi * 4 + r);
#pragma unroll
    for (int n = 0; n < 8; ++n)
#pragma unroll
      for (int r = 0; r < 4; ++r) o[n][r] *= srow[r];
    // P -> LDS (bf16), row q = lo, 64 keys padded to VLD
#pragma unroll
    for (int kt = 0; kt < 4; ++kt) {
      unsigned p01 = (unsigned)f2b(p[kt * 4]) | ((unsigned)f2b(p[kt * 4 + 1]) << 16);
      unsigned p23 = (unsigned)f2b(p[kt * 4 + 2]) | ((unsigned)f2b(p[kt * 4 + 3]) << 16);
      *(uint_a*)(Pw + lo * VLD + kt * 16 + hi * 4) = p01;
      *(uint_a*)(Pw + lo * VLD + kt * 16 + hi * 4 + 2) = p23;
    }
    __syncthreads();  // order P-store -> P-read (cross-lane via LDS)
    // PV: D[q = hi*4+r][d = n*16+lo] += P[q][k] * V[k][d]
#pragma unroll
    for (int c = 0; c < 2; ++c) {
      short8 pf = *(const short8_a*)(Pw + lo * VLD + c * 32 + hi * 8);
#pragma unroll
      for (int n = 0; n < 8; ++n) {
        short8 vf = *(const short8_a*)(Vs + (n * 16 + lo) * VLD + c * 32 + hi * 8);
        mfma_s(o[n], pf, vf);
      }
    }
  }
  // finalize: divide by row sums, write bf16
  float inv = 1.0f / l_run;
  float irow[4];
#pragma unroll
  for (int r = 0; r < 4; ++r) irow[r] = __shfl(inv, hi * 4 + r);
#pragma unroll
  for (int n = 0; n < 8; ++n)
#pragma unroll
    for (int r = 0; r < 4; ++r) {
      int q = q0 + w * 16 + hi * 4 + r;
      Ab[(long)q * 4096 + h * 128 + n * 16 + lo] = f2b(o[n][r] * irow[r]);
    }
}

// ---------------- host ----------------
extern "C" void kernel_launch(void* const* d_in, const int* in_sizes, int n_in,
                              void* d_out, int out_size, void* d_ws, size_t ws_size,
                              hipStream_t stream) {
  const float* x = (const float*)d_in[0];
  const float* wq = (const float*)d_in[1];
  const float* wk = (const float*)d_in[2];
  const float* wv = (const float*)d_in[3];
  const float* wo = (const float*)d_in[4];
  float* out = (float*)d_out;
  char* ws = (char*)d_ws;

  size_t off = 0;
  u16* xb = (u16*)(ws + off); off += 16777216;       // 2048x4096 bf16
  u16* wqb = (u16*)(ws + off); off += 33554432;      // 4096x4096 bf16
  u16* wkvb = (u16*)(ws + off); off += 16777216;     // [wk;wv] 2048x4096 bf16
  u16* wob = (u16*)(ws + off); off += 33554432;      // 4096x4096 bf16
  float* Qf = (float*)(ws + off); off += 33554432;   // 2048x4096 f32
  float* KVf = (float*)(ws + off); off += 16777216;  // 2048x2048 f32
  u16* Qb = (u16*)(ws + off); off += 16777216;       // 2048x4096 bf16
  u16* Kb = (u16*)(ws + off); off += 4194304;        // 2048x1024 bf16
  u16* Vtb = (u16*)(ws + off); off += 4194304;       // 1024x2048 bf16
  float* cost = (float*)(ws + off); off += 524288;   // 2048x64 f32
  float* sint = (float*)(ws + off); off += 524288;
  u16* Ab = (u16*)Qf;  // reuse Qf region (dead after RoPE)

  // casts
  k_cast<<<8192, 256, 0, stream>>>(x, xb, 2097152);
  k_cast<<<16384, 256, 0, stream>>>(wq, wqb, 4194304);
  k_cast<<<4096, 256, 0, stream>>>(wk, wkvb, 1048576);
  k_cast<<<4096, 256, 0, stream>>>(wv, wkvb + 4194304, 1048576);
  k_cast<<<16384, 256, 0, stream>>>(wo, wob, 4194304);
  k_tab<<<512, 256, 0, stream>>>(cost, sint);

  // projections
  k_gemm<<<512, 256, 0, stream>>>(xb, wqb, Qf, 2048, 4096, 4096);
  k_gemm<<<256, 256, 0, stream>>>(xb, wkvb, KVf, 2048, 2048, 4096);

  // rope + casts (scale 1/sqrt(128) folded into Q)
  k_rope<<<8192, 256, 0, stream>>>(Qf, 4096, Qb, 4096, cost, sint,
                                   0.08838834764831845f, 2097152);
  k_rope<<<2048, 256, 0, stream>>>(KVf, 2048, Kb, 1024, cost, sint, 1.0f, 524288);
  k_transpose<<<2048, 256, 0, stream>>>(KVf + 1024, 2048, Vtb, 2048);

  // attention
  k_attn<<<1024, 256, 0, stream>>>(Qb, Kb, Vtb, Ab);

  // output projection
  k_gemm<<<512, 256, 0, stream>>>(Ab, wob, out, 2048, 4096, 4096);
}

// Round 5
// 443.626 us; speedup vs baseline: 9.0311x; 1.4042x over previous
//
#include <hip/hip_runtime.h>

typedef unsigned short u16;
typedef short short8 __attribute__((ext_vector_type(8)));
typedef float f32x4 __attribute__((ext_vector_type(4)));
typedef unsigned short u16x4 __attribute__((ext_vector_type(4)));

typedef short8 short8_a __attribute__((may_alias));
typedef f32x4 f32x4_a __attribute__((may_alias));
typedef u16x4 u16x4_a __attribute__((may_alias));
typedef unsigned int uint_a __attribute__((may_alias));

__device__ __forceinline__ u16 f2b(float f) {
  unsigned u = __float_as_uint(f);
  u += 0x7FFFu + ((u >> 16) & 1u);
  return (u16)(u >> 16);
}

// Nop-free MFMA: safe when D is next touched >16cy away (GEMM pattern) or when
// a register-tied guard (below) sits between the cluster and the VALU reads.
__device__ __forceinline__ void mfma_b(f32x4& d, short8 a, short8 b) {
  asm("v_mfma_f32_16x16x32_bf16 %0, %1, %2, %0" : "+v"(d) : "v"(a), "v"(b));
}

// MFMA->VALU hazard guards. Register-tied ("+v" on the accumulators), so SSA
// dataflow forces: guard AFTER all MFMAs writing these regs, all VALU reads
// AFTER the guard. (A bare "memory"-clobber asm would NOT order register-only
// VALU ops — rule #18.)
__device__ __forceinline__ void guard4(f32x4& a, f32x4& b, f32x4& c, f32x4& d) {
  asm volatile("s_nop 7\n\ts_nop 7" : "+v"(a), "+v"(b), "+v"(c), "+v"(d));
}
__device__ __forceinline__ void guard8(f32x4* o) {
  asm volatile("s_nop 7\n\ts_nop 7"
               : "+v"(o[0]), "+v"(o[1]), "+v"(o[2]), "+v"(o[3]),
                 "+v"(o[4]), "+v"(o[5]), "+v"(o[6]), "+v"(o[7]));
}

__device__ __forceinline__ void gload16(const void* g, void* l) {
  __builtin_amdgcn_global_load_lds((__attribute__((address_space(1))) void*)(g),
                                   (__attribute__((address_space(3))) void*)(l),
                                   16, 0, 0);
}

// ---------------- fp32 -> bf16 cast ----------------
__global__ __launch_bounds__(256) void k_cast(const float* __restrict__ in,
                                              u16* __restrict__ out, int n4) {
  int i = blockIdx.x * 256 + threadIdx.x;
  if (i >= n4) return;
  f32x4 v = ((const f32x4_a*)in)[i];
  u16x4 o;
  o[0] = f2b(v[0]); o[1] = f2b(v[1]); o[2] = f2b(v[2]); o[3] = f2b(v[3]);
  ((u16x4_a*)out)[i] = o;
}

// ---------------- rope cos/sin table: [2048 s][64 j] ----------------
__global__ __launch_bounds__(256) void k_tab(float* __restrict__ cost,
                                             float* __restrict__ sint) {
  int i = blockIdx.x * 256 + threadIdx.x;  // 131072 total
  int s = i >> 6, j = i & 63;
  float freq = powf(500000.0f, -(float)j * (1.0f / 64.0f));
  float a = (float)s * freq;
  float sv, cv;
  sincosf(a, &sv, &cv);
  cost[i] = cv;
  sint[i] = sv;
}

// ---------------- RoPE + cast fp32->bf16 (interleaved pairs) ----------------
__global__ __launch_bounds__(256) void k_rope(const float* __restrict__ in, int ld_in,
                                              u16* __restrict__ out, int ncols,
                                              const float* __restrict__ cost,
                                              const float* __restrict__ sint,
                                              float scale, int total4) {
  int i = blockIdx.x * 256 + threadIdx.x;
  if (i >= total4) return;
  int base = i * 4;
  int s = base / ncols;
  int col = base - s * ncols;
  int j0 = (col & 127) >> 1;
  f32x4 v = *(const f32x4_a*)(in + (long)s * ld_in + col);
  int tb = (s << 6) + j0;
  float c0 = cost[tb], s0 = sint[tb];
  float c1 = cost[tb + 1], s1 = sint[tb + 1];
  u16x4 o;
  o[0] = f2b((v[0] * c0 - v[1] * s0) * scale);
  o[1] = f2b((v[0] * s0 + v[1] * c0) * scale);
  o[2] = f2b((v[2] * c1 - v[3] * s1) * scale);
  o[3] = f2b((v[2] * s1 + v[3] * c1) * scale);
  *(u16x4_a*)(out + (long)s * ncols + col) = o;
}

// ---------------- transpose + cast: V [2048 s][1024 c] -> [1024 c][2048 s] bf16 ----
__global__ __launch_bounds__(256) void k_transpose(const float* __restrict__ in, int ld,
                                                   u16* __restrict__ out, int out_ld) {
  __shared__ float tile[32][33];
  int tx = threadIdx.x & 31, ty = threadIdx.x >> 5;  // ty 0..7
  int sb = blockIdx.x & 63, cb = blockIdx.x >> 6;
  int s0 = sb << 5, c0 = cb << 5;
#pragma unroll
  for (int r = 0; r < 4; ++r)
    tile[ty + r * 8][tx] = in[(long)(s0 + ty + r * 8) * ld + c0 + tx];
  __syncthreads();
#pragma unroll
  for (int r = 0; r < 4; ++r)
    out[(long)(c0 + ty + r * 8) * out_ld + s0 + tx] = f2b(tile[tx][ty + r * 8]);
}

// ---------------- bf16 GEMM: C[M][N] = A[M][K] * B[N][K]^T (m97 structure) --------
__global__ __launch_bounds__(256, 2)
void k_gemm(const u16* __restrict__ A, const u16* __restrict__ B,
            float* __restrict__ C, int M, int N, int K) {
  __shared__ u16 As[4096];  // 128 rows x 32 k
  __shared__ u16 Bs[4096];
  const int tid = threadIdx.x;
  const int w = tid >> 6, lane = tid & 63;
  const int hi = lane >> 4, lo = lane & 15;
  const int nwg = gridDim.x;
  int bid = blockIdx.x;
  if ((nwg & 7) == 0) bid = (bid & 7) * (nwg >> 3) + (bid >> 3);  // XCD swizzle
  const int ntn = N >> 7;
  const int tm = bid / ntn, tn = bid - tm * ntn;
  const int m0 = tm << 7, n0 = tn << 7;
  const int wr = w >> 1, wc = w & 1;

  const int e0 = w * 512 + lane * 8;  // elem offset this lane stages (round 0)
  const int e1 = e0 + 2048;
  const u16* Ag0 = A + (long)(m0 + (e0 >> 5)) * K + (e0 & 31);
  const u16* Ag1 = A + (long)(m0 + (e1 >> 5)) * K + (e1 & 31);
  const u16* Bg0 = B + (long)(n0 + (e0 >> 5)) * K + (e0 & 31);
  const u16* Bg1 = B + (long)(n0 + (e1 >> 5)) * K + (e1 & 31);
  u16* As0 = As + w * 512;
  u16* As1 = As0 + 2048;
  u16* Bs0 = Bs + w * 512;
  u16* Bs1 = Bs0 + 2048;

  f32x4 acc[4][4] = {};
  const int aoff = (wr * 64 + lo) * 32 + hi * 8;
  const int boff = (wc * 64 + lo) * 32 + hi * 8;

  for (int k0 = 0; k0 < K; k0 += 32) {
    __syncthreads();
    gload16(Ag0 + k0, As0);
    gload16(Ag1 + k0, As1);
    gload16(Bg0 + k0, Bs0);
    gload16(Bg1 + k0, Bs1);
    __syncthreads();
    short8 af[4], bf[4];
#pragma unroll
    for (int m = 0; m < 4; ++m) af[m] = *(const short8_a*)(As + aoff + m * 512);
#pragma unroll
    for (int n = 0; n < 4; ++n) bf[n] = *(const short8_a*)(Bs + boff + n * 512);
#pragma unroll
    for (int m = 0; m < 4; ++m)
#pragma unroll
      for (int n = 0; n < 4; ++n) mfma_b(acc[m][n], af[m], bf[n]);
  }

#pragma unroll
  for (int m = 0; m < 4; ++m) {
    const int row0 = m0 + wr * 64 + m * 16 + hi * 4;
#pragma unroll
    for (int n = 0; n < 4; ++n) {
      const int col = n0 + wc * 64 + n * 16 + lo;
#pragma unroll
      for (int r = 0; r < 4; ++r)
        C[(long)(row0 + r) * N + col] = acc[m][n][r];
    }
  }
}

// ---------------- causal GQA flash attention (MFMA, cluster-guarded) ----------------
// Qb: [2048][4096] bf16 (pre-scaled by 1/sqrt(128)), Kb: [2048][1024] bf16,
// Vt: [1024][2048] bf16 (d-major), Ab out: [2048][4096] bf16.
#define KLD 136  // 128 + 8 pad (elems)
#define VLD 72   // 64 + 8 pad (elems)
__global__ __launch_bounds__(256, 2)
void k_attn(const u16* __restrict__ Qb, const u16* __restrict__ Kb,
            const u16* __restrict__ Vt, u16* __restrict__ Ab) {
  __shared__ u16 Ks[64 * KLD];
  __shared__ u16 Vs[128 * VLD];
  __shared__ u16 Ps[4 * 16 * VLD];

  const int tid = threadIdx.x;
  const int w = tid >> 6, lane = tid & 63;
  const int hi = lane >> 4, lo = lane & 15;
  // heavy-first: qt descending in launch order (block work ~ qt+1)
  const int qt = 31 - (blockIdx.x >> 5);
  const int h = blockIdx.x & 31;
  const int hkv = h >> 2;
  const int q0 = qt * 64;
  const int qrow = q0 + w * 16 + lo;  // score-q for this lane (D col = lo)

  short8 qf[4];
#pragma unroll
  for (int c = 0; c < 4; ++c)
    qf[c] = *(const short8_a*)(Qb + (long)qrow * 4096 + h * 128 + c * 32 + hi * 8);

  f32x4 o[8] = {};
  float m_run = -1e30f, l_run = 0.f;
  u16* Pw = Ps + w * (16 * VLD);

  const int ntiles = qt + 1;
  for (int t = 0; t < ntiles; ++t) {
    const int kv0 = t * 64;
    __syncthreads();
    // stage K tile [64][128] -> padded LDS
#pragma unroll
    for (int r = 0; r < 4; ++r) {
      int i = r * 256 + tid;
      int key = i >> 4, d8 = (i & 15) * 8;
      short8 v = *(const short8_a*)(Kb + (long)(kv0 + key) * 1024 + hkv * 128 + d8);
      *(short8_a*)(Ks + key * KLD + d8) = v;
    }
    // stage V^T tile [128][64] -> padded LDS
#pragma unroll
    for (int r = 0; r < 4; ++r) {
      int i = r * 256 + tid;
      int dd = i >> 3, k8 = (i & 7) * 8;
      short8 v = *(const short8_a*)(Vt + (long)hkv * 262144 + (long)dd * 2048 + kv0 + k8);
      *(short8_a*)(Vs + dd * VLD + k8) = v;
    }
    __syncthreads();

    // swapped QK^T: D[key = hi*4+r (+16*kt)][q = lo]
    f32x4 sc[4] = {};
#pragma unroll
    for (int c = 0; c < 4; ++c) {
#pragma unroll
      for (int kt = 0; kt < 4; ++kt) {
        short8 kf = *(const short8_a*)(Ks + (kt * 16 + lo) * KLD + c * 32 + hi * 8);
        mfma_b(sc[kt], kf, qf[c]);
      }
    }
    guard4(sc[0], sc[1], sc[2], sc[3]);  // MFMA->VALU hazard fence for sc reads

    if (t == ntiles - 1) {  // diagonal tile: causal mask
#pragma unroll
      for (int kt = 0; kt < 4; ++kt)
#pragma unroll
        for (int r = 0; r < 4; ++r) {
          int key = kv0 + kt * 16 + hi * 4 + r;
          if (key > qrow) sc[kt][r] = -1e30f;
        }
    }
    // online softmax (row q = lo; lanes hi=0..3 hold 16 keys each)
    float tmax = -1e30f;
#pragma unroll
    for (int kt = 0; kt < 4; ++kt)
#pragma unroll
      for (int r = 0; r < 4; ++r) tmax = fmaxf(tmax, sc[kt][r]);
    tmax = fmaxf(tmax, __shfl_xor(tmax, 16));
    tmax = fmaxf(tmax, __shfl_xor(tmax, 32));
    float m_new = fmaxf(m_run, tmax);
    float scale = __expf(m_run - m_new);
    float psum = 0.f;
    float p[16];
#pragma unroll
    for (int kt = 0; kt < 4; ++kt)
#pragma unroll
      for (int r = 0; r < 4; ++r) {
        float pv = __expf(sc[kt][r] - m_new);
        p[kt * 4 + r] = pv;
        psum += pv;
      }
    psum += __shfl_xor(psum, 16);
    psum += __shfl_xor(psum, 32);
    l_run = l_run * scale + psum;
    m_run = m_new;
    // rescale O (PV-D rows q = hi*4+r need the scale of score-lane lo = hi*4+r)
    // (reads o written by PREVIOUS tile's PV cluster — separated by 2 barriers
    //  + staging, far beyond the hazard window: no guard needed)
    float srow[4];
#pragma unroll
    for (int r = 0; r < 4; ++r) srow[r] = __shfl(scale, hi * 4 + r);
#pragma unroll
    for (int n = 0; n < 8; ++n)
#pragma unroll
      for (int r = 0; r < 4; ++r) o[n][r] *= srow[r];
    // P -> LDS (bf16), row q = lo, 64 keys padded to VLD
#pragma unroll
    for (int kt = 0; kt < 4; ++kt) {
      unsigned p01 = (unsigned)f2b(p[kt * 4]) | ((unsigned)f2b(p[kt * 4 + 1]) << 16);
      unsigned p23 = (unsigned)f2b(p[kt * 4 + 2]) | ((unsigned)f2b(p[kt * 4 + 3]) << 16);
      *(uint_a*)(Pw + lo * VLD + kt * 16 + hi * 4) = p01;
      *(uint_a*)(Pw + lo * VLD + kt * 16 + hi * 4 + 2) = p23;
    }
    __syncthreads();  // order P-store -> P-read (cross-lane via LDS)
    // PV: D[q = hi*4+r][d = n*16+lo] += P[q][k] * V[k][d]
#pragma unroll
    for (int c = 0; c < 2; ++c) {
      short8 pf = *(const short8_a*)(Pw + lo * VLD + c * 32 + hi * 8);
#pragma unroll
      for (int n = 0; n < 8; ++n) {
        short8 vf = *(const short8_a*)(Vs + (n * 16 + lo) * VLD + c * 32 + hi * 8);
        mfma_b(o[n], pf, vf);
      }
    }
  }
  guard8(o);  // MFMA->VALU hazard fence before epilogue reads of o

  // finalize: divide by row sums, write bf16
  float inv = 1.0f / l_run;
  float irow[4];
#pragma unroll
  for (int r = 0; r < 4; ++r) irow[r] = __shfl(inv, hi * 4 + r);
#pragma unroll
  for (int n = 0; n < 8; ++n)
#pragma unroll
    for (int r = 0; r < 4; ++r) {
      int q = q0 + w * 16 + hi * 4 + r;
      Ab[(long)q * 4096 + h * 128 + n * 16 + lo] = f2b(o[n][r] * irow[r]);
    }
}

// ---------------- host ----------------
extern "C" void kernel_launch(void* const* d_in, const int* in_sizes, int n_in,
                              void* d_out, int out_size, void* d_ws, size_t ws_size,
                              hipStream_t stream) {
  const float* x = (const float*)d_in[0];
  const float* wq = (const float*)d_in[1];
  const float* wk = (const float*)d_in[2];
  const float* wv = (const float*)d_in[3];
  const float* wo = (const float*)d_in[4];
  float* out = (float*)d_out;
  char* ws = (char*)d_ws;

  size_t off = 0;
  u16* xb = (u16*)(ws + off); off += 16777216;       // 2048x4096 bf16
  u16* wqb = (u16*)(ws + off); off += 33554432;      // 4096x4096 bf16
  u16* wkvb = (u16*)(ws + off); off += 16777216;     // [wk;wv] 2048x4096 bf16
  u16* wob = (u16*)(ws + off); off += 33554432;      // 4096x4096 bf16
  float* Qf = (float*)(ws + off); off += 33554432;   // 2048x4096 f32
  float* KVf = (float*)(ws + off); off += 16777216;  // 2048x2048 f32
  u16* Qb = (u16*)(ws + off); off += 16777216;       // 2048x4096 bf16
  u16* Kb = (u16*)(ws + off); off += 4194304;        // 2048x1024 bf16
  u16* Vtb = (u16*)(ws + off); off += 4194304;       // 1024x2048 bf16
  float* cost = (float*)(ws + off); off += 524288;   // 2048x64 f32
  float* sint = (float*)(ws + off); off += 524288;
  u16* Ab = (u16*)Qf;  // reuse Qf region (dead after RoPE)

  // casts
  k_cast<<<8192, 256, 0, stream>>>(x, xb, 2097152);
  k_cast<<<16384, 256, 0, stream>>>(wq, wqb, 4194304);
  k_cast<<<4096, 256, 0, stream>>>(wk, wkvb, 1048576);
  k_cast<<<4096, 256, 0, stream>>>(wv, wkvb + 4194304, 1048576);
  k_cast<<<16384, 256, 0, stream>>>(wo, wob, 4194304);
  k_tab<<<512, 256, 0, stream>>>(cost, sint);

  // projections
  k_gemm<<<512, 256, 0, stream>>>(xb, wqb, Qf, 2048, 4096, 4096);
  k_gemm<<<256, 256, 0, stream>>>(xb, wkvb, KVf, 2048, 2048, 4096);

  // rope + casts (scale 1/sqrt(128) folded into Q)
  k_rope<<<8192, 256, 0, stream>>>(Qf, 4096, Qb, 4096, cost, sint,
                                   0.08838834764831845f, 2097152);
  k_rope<<<2048, 256, 0, stream>>>(KVf, 2048, Kb, 1024, cost, sint, 1.0f, 524288);
  k_transpose<<<2048, 256, 0, stream>>>(KVf + 1024, 2048, Vtb, 2048);

  // attention
  k_attn<<<1024, 256, 0, stream>>>(Qb, Kb, Vtb, Ab);

  // output projection
  k_gemm<<<512, 256, 0, stream>>>(Ab, wob, out, 2048, 4096, 4096);
}

// Round 6
// 385.628 us; speedup vs baseline: 10.3894x; 1.1504x over previous
//
#include <hip/hip_runtime.h>

typedef unsigned short u16;
typedef short short8 __attribute__((ext_vector_type(8)));
typedef float f32x4 __attribute__((ext_vector_type(4)));
typedef unsigned short u16x4 __attribute__((ext_vector_type(4)));

typedef short8 short8_a __attribute__((may_alias));
typedef f32x4 f32x4_a __attribute__((may_alias));
typedef u16x4 u16x4_a __attribute__((may_alias));
typedef unsigned int uint_a __attribute__((may_alias));

__device__ __forceinline__ u16 f2b(float f) {
  unsigned u = __float_as_uint(f);
  u += 0x7FFFu + ((u >> 16) & 1u);
  return (u16)(u >> 16);
}

// Nop-free MFMA: safe when D is next read >16cy away or behind a guard below.
__device__ __forceinline__ void mfma_b(f32x4& d, short8 a, short8 b) {
  asm("v_mfma_f32_16x16x32_bf16 %0, %1, %2, %0" : "+v"(d) : "v"(a), "v"(b));
}

// MFMA->VALU hazard guards, register-tied (dataflow-ordered; rule #18 safe).
__device__ __forceinline__ void guard4(f32x4& a, f32x4& b, f32x4& c, f32x4& d) {
  asm volatile("s_nop 7\n\ts_nop 7" : "+v"(a), "+v"(b), "+v"(c), "+v"(d));
}
__device__ __forceinline__ void guard8(f32x4* o) {
  asm volatile("s_nop 7\n\ts_nop 7"
               : "+v"(o[0]), "+v"(o[1]), "+v"(o[2]), "+v"(o[3]),
                 "+v"(o[4]), "+v"(o[5]), "+v"(o[6]), "+v"(o[7]));
}

__device__ __forceinline__ void gload16(const void* g, void* l) {
  __builtin_amdgcn_global_load_lds((__attribute__((address_space(1))) void*)(g),
                                   (__attribute__((address_space(3))) void*)(l),
                                   16, 0, 0);
}

// ---------------- fp32 -> bf16 cast ----------------
__global__ __launch_bounds__(256) void k_cast(const float* __restrict__ in,
                                              u16* __restrict__ out, int n4) {
  int i = blockIdx.x * 256 + threadIdx.x;
  if (i >= n4) return;
  f32x4 v = ((const f32x4_a*)in)[i];
  u16x4 o;
  o[0] = f2b(v[0]); o[1] = f2b(v[1]); o[2] = f2b(v[2]); o[3] = f2b(v[3]);
  ((u16x4_a*)out)[i] = o;
}

// ---------------- rope cos/sin table: [2048 s][64 j] ----------------
__global__ __launch_bounds__(256) void k_tab(float* __restrict__ cost,
                                             float* __restrict__ sint) {
  int i = blockIdx.x * 256 + threadIdx.x;  // 131072 total
  int s = i >> 6, j = i & 63;
  float freq = powf(500000.0f, -(float)j * (1.0f / 64.0f));
  float a = (float)s * freq;
  float sv, cv;
  sincosf(a, &sv, &cv);
  cost[i] = cv;
  sint[i] = sv;
}

// ---- bf16 GEMM, 2-phase prefetch: C[M][N] = A[M][K] * B[N][K]^T ----
// EPI=0: store f32 C.  EPI=1: fused QKV epilogue (N=6144): cols [0,4096) ->
// RoPE+scale -> Qb; [4096,5120) -> RoPE -> Kb; [5120,6144) -> transpose -> Vt.
#define QK_SCALE 0.08838834764831845f
template <int EPI>
__global__ __launch_bounds__(256, 2)
void k_gemm_t(const u16* __restrict__ A, const u16* __restrict__ B,
              float* __restrict__ C, int M, int N, int K,
              const float* __restrict__ cost, const float* __restrict__ sint,
              u16* __restrict__ Qb, u16* __restrict__ Kb, u16* __restrict__ Vt) {
  __shared__ u16 As[2][4096];  // [buf][128 rows x 32 k]
  __shared__ u16 Bs[2][4096];
  const int tid = threadIdx.x;
  const int w = tid >> 6, lane = tid & 63;
  const int hi = lane >> 4, lo = lane & 15;
  const int nwg = gridDim.x;
  int bid = blockIdx.x;
  if ((nwg & 7) == 0) bid = (bid & 7) * (nwg >> 3) + (bid >> 3);  // XCD swizzle
  const int ntn = N >> 7;
  const int tm = bid / ntn, tn = bid - tm * ntn;
  const int m0 = tm << 7, n0 = tn << 7;
  const int wr = w >> 1, wc = w & 1;

  const int e0 = w * 512 + lane * 8;
  const int e1 = e0 + 2048;
  const u16* Ag0 = A + (long)(m0 + (e0 >> 5)) * K + (e0 & 31);
  const u16* Ag1 = A + (long)(m0 + (e1 >> 5)) * K + (e1 & 31);
  const u16* Bg0 = B + (long)(n0 + (e0 >> 5)) * K + (e0 & 31);
  const u16* Bg1 = B + (long)(n0 + (e1 >> 5)) * K + (e1 & 31);
  const int sb = w * 512;  // wave-uniform LDS staging base (elems)

  f32x4 acc[4][4] = {};
  const int aoff = (wr * 64 + lo) * 32 + hi * 8;
  const int boff = (wc * 64 + lo) * 32 + hi * 8;

  const int nt = K >> 5;
  int cur = 0;
  // prologue: stage tile 0
  gload16(Ag0, &As[0][sb]);
  gload16(Ag1, &As[0][sb + 2048]);
  gload16(Bg0, &Bs[0][sb]);
  gload16(Bg1, &Bs[0][sb + 2048]);
  __syncthreads();
  for (int t = 0; t < nt; ++t) {
    if (t + 1 < nt) {  // issue next-tile prefetch BEFORE compute (T3 minimum)
      const int k0 = (t + 1) << 5;
      const int nx = cur ^ 1;
      gload16(Ag0 + k0, &As[nx][sb]);
      gload16(Ag1 + k0, &As[nx][sb + 2048]);
      gload16(Bg0 + k0, &Bs[nx][sb]);
      gload16(Bg1 + k0, &Bs[nx][sb + 2048]);
    }
    short8 af[4], bf[4];
#pragma unroll
    for (int m = 0; m < 4; ++m) af[m] = *(const short8_a*)(&As[cur][aoff + m * 512]);
#pragma unroll
    for (int n = 0; n < 4; ++n) bf[n] = *(const short8_a*)(&Bs[cur][boff + n * 512]);
#pragma unroll
    for (int m = 0; m < 4; ++m)
#pragma unroll
      for (int n = 0; n < 4; ++n) mfma_b(acc[m][n], af[m], bf[n]);
    __syncthreads();  // implicit vmcnt(0): drains this iter's prefetch
    cur ^= 1;
  }
  guard8(&acc[0][0]);  // MFMA->VALU hazard fence before epilogue acc reads
  guard8(&acc[2][0]);

  if constexpr (EPI == 0) {
#pragma unroll
    for (int m = 0; m < 4; ++m) {
      const int row0 = m0 + wr * 64 + m * 16 + hi * 4;
#pragma unroll
      for (int n = 0; n < 4; ++n) {
        const int col = n0 + wc * 64 + n * 16 + lo;
#pragma unroll
        for (int r = 0; r < 4; ++r)
          C[(long)(row0 + r) * N + col] = acc[m][n][r];
      }
    }
  } else {
    if (n0 < 5120) {  // Q or K columns: RoPE (pair partner lives in lane lo^1)
      const bool isQ = (n0 < 4096);
#pragma unroll
      for (int m = 0; m < 4; ++m) {
        const int row0 = m0 + wr * 64 + m * 16 + hi * 4;
#pragma unroll
        for (int n = 0; n < 4; ++n) {
          const int c = n0 + wc * 64 + n * 16 + lo;
          const int j0 = (c & 127) >> 1;
          const bool even = ((c & 1) == 0);
#pragma unroll
          for (int r = 0; r < 4; ++r) {
            float own = acc[m][n][r];
            float part = __shfl_xor(own, 1);
            const int s_ = row0 + r;
            const float cv = cost[s_ * 64 + j0];
            const float sv = sint[s_ * 64 + j0];
            float res = even ? (own * cv - part * sv) : (part * sv + own * cv);
            if (isQ)
              Qb[(long)s_ * 4096 + c] = f2b(res * QK_SCALE);
            else
              Kb[(long)s_ * 1024 + (c - 4096)] = f2b(res);
          }
        }
      }
    } else {  // V columns: transposed bf16 store Vt[c][s], 4 rows packed
#pragma unroll
      for (int m = 0; m < 4; ++m) {
        const int row0 = m0 + wr * 64 + m * 16 + hi * 4;
#pragma unroll
        for (int n = 0; n < 4; ++n) {
          const int vc = n0 - 5120 + wc * 64 + n * 16 + lo;
          u16x4 pk;
#pragma unroll
          for (int r = 0; r < 4; ++r) pk[r] = f2b(acc[m][n][r]);
          *(u16x4_a*)(Vt + (long)vc * 2048 + row0) = pk;
        }
      }
    }
  }
}

// ---------------- causal GQA flash attention (MFMA, cluster-guarded) ----------------
// Qb: [2048][4096] bf16 (pre-scaled), Kb: [2048][1024] bf16,
// Vt: [1024][2048] bf16 (d-major), Ab out: [2048][4096] bf16.
#define KLD 136  // 128 + 8 pad (elems)
#define VLD 72   // 64 + 8 pad (elems)
__global__ __launch_bounds__(256, 2)
void k_attn(const u16* __restrict__ Qb, const u16* __restrict__ Kb,
            const u16* __restrict__ Vt, u16* __restrict__ Ab) {
  __shared__ u16 Ks[64 * KLD];
  __shared__ u16 Vs[128 * VLD];
  __shared__ u16 Ps[4 * 16 * VLD];

  const int tid = threadIdx.x;
  const int w = tid >> 6, lane = tid & 63;
  const int hi = lane >> 4, lo = lane & 15;
  // heavy-first: qt descending in launch order (block work ~ qt+1)
  const int qt = 31 - (blockIdx.x >> 5);
  const int h = blockIdx.x & 31;
  const int hkv = h >> 2;
  const int q0 = qt * 64;
  const int qrow = q0 + w * 16 + lo;  // score-q for this lane (D col = lo)

  short8 qf[4];
#pragma unroll
  for (int c = 0; c < 4; ++c)
    qf[c] = *(const short8_a*)(Qb + (long)qrow * 4096 + h * 128 + c * 32 + hi * 8);

  f32x4 o[8] = {};
  float m_run = -1e30f, l_run = 0.f;
  u16* Pw = Ps + w * (16 * VLD);

  const int ntiles = qt + 1;
  for (int t = 0; t < ntiles; ++t) {
    const int kv0 = t * 64;
    __syncthreads();
    // stage K tile [64][128] -> padded LDS
#pragma unroll
    for (int r = 0; r < 4; ++r) {
      int i = r * 256 + tid;
      int key = i >> 4, d8 = (i & 15) * 8;
      short8 v = *(const short8_a*)(Kb + (long)(kv0 + key) * 1024 + hkv * 128 + d8);
      *(short8_a*)(Ks + key * KLD + d8) = v;
    }
    // stage V^T tile [128][64] -> padded LDS
#pragma unroll
    for (int r = 0; r < 4; ++r) {
      int i = r * 256 + tid;
      int dd = i >> 3, k8 = (i & 7) * 8;
      short8 v = *(const short8_a*)(Vt + (long)hkv * 262144 + (long)dd * 2048 + kv0 + k8);
      *(short8_a*)(Vs + dd * VLD + k8) = v;
    }
    __syncthreads();

    // swapped QK^T: D[key = hi*4+r (+16*kt)][q = lo]
    f32x4 sc[4] = {};
#pragma unroll
    for (int c = 0; c < 4; ++c) {
#pragma unroll
      for (int kt = 0; kt < 4; ++kt) {
        short8 kf = *(const short8_a*)(Ks + (kt * 16 + lo) * KLD + c * 32 + hi * 8);
        mfma_b(sc[kt], kf, qf[c]);
      }
    }
    guard4(sc[0], sc[1], sc[2], sc[3]);  // MFMA->VALU hazard fence

    if (t == ntiles - 1) {  // diagonal tile: causal mask
#pragma unroll
      for (int kt = 0; kt < 4; ++kt)
#pragma unroll
        for (int r = 0; r < 4; ++r) {
          int key = kv0 + kt * 16 + hi * 4 + r;
          if (key > qrow) sc[kt][r] = -1e30f;
        }
    }
    // online softmax (row q = lo; lanes hi=0..3 hold 16 keys each)
    float tmax = -1e30f;
#pragma unroll
    for (int kt = 0; kt < 4; ++kt)
#pragma unroll
      for (int r = 0; r < 4; ++r) tmax = fmaxf(tmax, sc[kt][r]);
    tmax = fmaxf(tmax, __shfl_xor(tmax, 16));
    tmax = fmaxf(tmax, __shfl_xor(tmax, 32));
    float m_new = fmaxf(m_run, tmax);
    float scale = __expf(m_run - m_new);
    float psum = 0.f;
    float p[16];
#pragma unroll
    for (int kt = 0; kt < 4; ++kt)
#pragma unroll
      for (int r = 0; r < 4; ++r) {
        float pv = __expf(sc[kt][r] - m_new);
        p[kt * 4 + r] = pv;
        psum += pv;
      }
    psum += __shfl_xor(psum, 16);
    psum += __shfl_xor(psum, 32);
    l_run = l_run * scale + psum;
    m_run = m_new;
    // rescale O (PV-D rows q = hi*4+r need the scale of score-lane lo = hi*4+r)
    float srow[4];
#pragma unroll
    for (int r = 0; r < 4; ++r) srow[r] = __shfl(scale, hi * 4 + r);
#pragma unroll
    for (int n = 0; n < 8; ++n)
#pragma unroll
      for (int r = 0; r < 4; ++r) o[n][r] *= srow[r];
    // P -> LDS (bf16), row q = lo, 64 keys padded to VLD
#pragma unroll
    for (int kt = 0; kt < 4; ++kt) {
      unsigned p01 = (unsigned)f2b(p[kt * 4]) | ((unsigned)f2b(p[kt * 4 + 1]) << 16);
      unsigned p23 = (unsigned)f2b(p[kt * 4 + 2]) | ((unsigned)f2b(p[kt * 4 + 3]) << 16);
      *(uint_a*)(Pw + lo * VLD + kt * 16 + hi * 4) = p01;
      *(uint_a*)(Pw + lo * VLD + kt * 16 + hi * 4 + 2) = p23;
    }
    __syncthreads();  // order P-store -> P-read (cross-lane via LDS)
    // PV: D[q = hi*4+r][d = n*16+lo] += P[q][k] * V[k][d]
#pragma unroll
    for (int c = 0; c < 2; ++c) {
      short8 pf = *(const short8_a*)(Pw + lo * VLD + c * 32 + hi * 8);
#pragma unroll
      for (int n = 0; n < 8; ++n) {
        short8 vf = *(const short8_a*)(Vs + (n * 16 + lo) * VLD + c * 32 + hi * 8);
        mfma_b(o[n], pf, vf);
      }
    }
  }
  guard8(o);  // MFMA->VALU hazard fence before epilogue reads of o

  // finalize: divide by row sums, write bf16
  float inv = 1.0f / l_run;
  float irow[4];
#pragma unroll
  for (int r = 0; r < 4; ++r) irow[r] = __shfl(inv, hi * 4 + r);
#pragma unroll
  for (int n = 0; n < 8; ++n)
#pragma unroll
    for (int r = 0; r < 4; ++r) {
      int q = q0 + w * 16 + hi * 4 + r;
      Ab[(long)q * 4096 + h * 128 + n * 16 + lo] = f2b(o[n][r] * irow[r]);
    }
}

// ---------------- host ----------------
extern "C" void kernel_launch(void* const* d_in, const int* in_sizes, int n_in,
                              void* d_out, int out_size, void* d_ws, size_t ws_size,
                              hipStream_t stream) {
  const float* x = (const float*)d_in[0];
  const float* wq = (const float*)d_in[1];
  const float* wk = (const float*)d_in[2];
  const float* wv = (const float*)d_in[3];
  const float* wo = (const float*)d_in[4];
  float* out = (float*)d_out;
  char* ws = (char*)d_ws;

  size_t off = 0;
  u16* xb = (u16*)(ws + off); off += 16777216;     // x 2048x4096 bf16
  u16* wB = (u16*)(ws + off); off += 50331648;     // [wq;wk;wv] 6144x4096 bf16
  u16* wob = (u16*)(ws + off); off += 33554432;    // wo 4096x4096 bf16
  u16* Qb = (u16*)(ws + off); off += 16777216;     // 2048x4096 bf16 (roped, scaled)
  u16* Kb = (u16*)(ws + off); off += 4194304;      // 2048x1024 bf16 (roped)
  u16* Vtb = (u16*)(ws + off); off += 4194304;     // 1024x2048 bf16 (transposed)
  float* cost = (float*)(ws + off); off += 524288; // 2048x64 f32
  float* sint = (float*)(ws + off); off += 524288;
  u16* Ab = (u16*)(ws + off); off += 16777216;     // attn out 2048x4096 bf16

  // casts (wB rows: wq 0..4095, wk 4096..5119, wv 5120..6143)
  k_cast<<<8192, 256, 0, stream>>>(x, xb, 2097152);
  k_cast<<<16384, 256, 0, stream>>>(wq, wB, 4194304);
  k_cast<<<4096, 256, 0, stream>>>(wk, wB + 16777216, 1048576);
  k_cast<<<4096, 256, 0, stream>>>(wv, wB + 20971520, 1048576);
  k_cast<<<16384, 256, 0, stream>>>(wo, wob, 4194304);
  k_tab<<<512, 256, 0, stream>>>(cost, sint);

  // fused QKV projection: GEMM + RoPE/scale/transpose epilogue
  k_gemm_t<1><<<768, 256, 0, stream>>>(xb, wB, nullptr, 2048, 6144, 4096,
                                       cost, sint, Qb, Kb, Vtb);

  // attention
  k_attn<<<1024, 256, 0, stream>>>(Qb, Kb, Vtb, Ab);

  // output projection
  k_gemm_t<0><<<512, 256, 0, stream>>>(Ab, wob, out, 2048, 4096, 4096,
                                       nullptr, nullptr, nullptr, nullptr, nullptr);
}

// Round 7
// 378.292 us; speedup vs baseline: 10.5908x; 1.0194x over previous
//
#include <hip/hip_runtime.h>

typedef unsigned short u16;
typedef short short8 __attribute__((ext_vector_type(8)));
typedef float f32x4 __attribute__((ext_vector_type(4)));
typedef unsigned short u16x4 __attribute__((ext_vector_type(4)));

typedef short8 short8_a __attribute__((may_alias));
typedef f32x4 f32x4_a __attribute__((may_alias));
typedef u16x4 u16x4_a __attribute__((may_alias));
typedef unsigned int uint_a __attribute__((may_alias));

__device__ __forceinline__ u16 f2b(float f) {
  unsigned u = __float_as_uint(f);
  u += 0x7FFFu + ((u >> 16) & 1u);
  return (u16)(u >> 16);
}

// Nop-free MFMA: safe when D is next read >16cy away or behind a guard below.
__device__ __forceinline__ void mfma_b(f32x4& d, short8 a, short8 b) {
  asm("v_mfma_f32_16x16x32_bf16 %0, %1, %2, %0" : "+v"(d) : "v"(a), "v"(b));
}

// MFMA->VALU hazard guards, register-tied (dataflow-ordered; rule #18 safe).
__device__ __forceinline__ void guard4(f32x4& a, f32x4& b, f32x4& c, f32x4& d) {
  asm volatile("s_nop 7\n\ts_nop 7" : "+v"(a), "+v"(b), "+v"(c), "+v"(d));
}
__device__ __forceinline__ void guard8(f32x4* o) {
  asm volatile("s_nop 7\n\ts_nop 7"
               : "+v"(o[0]), "+v"(o[1]), "+v"(o[2]), "+v"(o[3]),
                 "+v"(o[4]), "+v"(o[5]), "+v"(o[6]), "+v"(o[7]));
}

__device__ __forceinline__ void gload16(const void* g, void* l) {
  __builtin_amdgcn_global_load_lds((__attribute__((address_space(1))) void*)(g),
                                   (__attribute__((address_space(3))) void*)(l),
                                   16, 0, 0);
}

// counted-vmcnt barriers (single asm: memory ops cannot cross; vmcnt never 0
// in steady state so prefetch loads stay in flight across the barrier — T4)
__device__ __forceinline__ void bar_v4() {
  asm volatile("s_waitcnt vmcnt(4)\n\ts_barrier" ::: "memory");
}
__device__ __forceinline__ void bar_v0() {
  asm volatile("s_waitcnt vmcnt(0)\n\ts_barrier" ::: "memory");
}

// ---------------- merged prep: all fp32->bf16 casts + rope table ----------------
// vec4 segments: [0,2097152) x | [..,6291456) wq | [..,7340032) wk
// [..,8388608) wv | [..,12582912) wo | then 131072 table entries (512 blocks).
__global__ __launch_bounds__(256)
void k_prep(const float* __restrict__ x, const float* __restrict__ wq,
            const float* __restrict__ wk, const float* __restrict__ wv,
            const float* __restrict__ wo, u16* __restrict__ xb,
            u16* __restrict__ wB, u16* __restrict__ wob,
            float* __restrict__ cost, float* __restrict__ sint) {
  const long i = (long)blockIdx.x * 256 + threadIdx.x;
  const float* src;
  u16* dst;
  long j;
  if (i < 6291456) {
    if (i < 2097152) { src = x; dst = xb; j = i; }
    else { src = wq; dst = wB; j = i - 2097152; }
  } else if (i < 8388608) {
    if (i < 7340032) { src = wk; dst = wB + 16777216; j = i - 6291456; }
    else { src = wv; dst = wB + 20971520; j = i - 7340032; }
  } else if (i < 12582912) {
    src = wo; dst = wob; j = i - 8388608;
  } else {
    long ti = i - 12582912;  // [0, 131072): rope table, s = ti>>6, j = ti&63
    int s = (int)(ti >> 6), jj = (int)(ti & 63);
    float freq = powf(500000.0f, -(float)jj * (1.0f / 64.0f));
    float a = (float)s * freq;
    float sv, cv;
    sincosf(a, &sv, &cv);
    cost[ti] = cv;
    sint[ti] = sv;
    return;
  }
  f32x4 v = ((const f32x4_a*)src)[j];
  u16x4 o;
  o[0] = f2b(v[0]); o[1] = f2b(v[1]); o[2] = f2b(v[2]); o[3] = f2b(v[3]);
  ((u16x4_a*)dst)[j] = o;
}

// ---- bf16 GEMM: C[M][N] = A[M][K]*B[N][K]^T. 128x128 tile, BK=32, triple-
// buffered LDS, counted-vmcnt pipeline (prefetch distance 2), swizzled LDS.
// Swizzle (both-sides, rule #21): linear gload_lds dest; global source slot
// pre-XORed; ds_read slot XORed with (row>>1)&3 -> ~2-way banks (was 8-way).
// EPI=0: f32 C store. EPI=1: fused QKV epilogue (N=6144): [0,4096)->RoPE*scale
// ->Qb; [4096,5120)->RoPE->Kb; [5120,6144)->transpose->Vt.
#define QK_SCALE 0.08838834764831845f
template <int EPI>
__global__ __launch_bounds__(256, 2)
void k_gemm_t(const u16* __restrict__ A, const u16* __restrict__ B,
              float* __restrict__ C, int M, int N, int K,
              const float* __restrict__ cost, const float* __restrict__ sint,
              u16* __restrict__ Qb, u16* __restrict__ Kb, u16* __restrict__ Vt) {
  __shared__ u16 As[12288];  // 3 bufs x (128 rows x 32 k)
  __shared__ u16 Bs[12288];
  const int tid = threadIdx.x;
  const int w = tid >> 6, lane = tid & 63;
  const int hi = lane >> 4, lo = lane & 15;
  const int nwg = gridDim.x;
  int bid = blockIdx.x;
  if ((nwg & 7) == 0) bid = (bid & 7) * (nwg >> 3) + (bid >> 3);  // XCD swizzle
  const int ntn = N >> 7;
  const int tm = bid / ntn, tn = bid - tm * ntn;
  const int m0 = tm << 7, n0 = tn << 7;
  const int wr = w >> 1, wc = w & 1;

  // staging: lane lands at row (w*16 + l>>2), slot (l&3); source slot pre-XORed
  const int rowl = w * 16 + (lane >> 2);
  const int ks = (((lane & 3) ^ ((lane >> 3) & 3)) << 3);  // elems
  const u16* Ag0 = A + (long)(m0 + rowl) * K + ks;
  const u16* Ag1 = A + (long)(m0 + 64 + rowl) * K + ks;
  const u16* Bg0 = B + (long)(n0 + rowl) * K + ks;
  const u16* Bg1 = B + (long)(n0 + 64 + rowl) * K + ks;
  const int sb = w * 512;  // wave-uniform LDS chunk base (elems)

  f32x4 acc[4][4] = {};
  const int hs = hi ^ ((lo >> 1) & 3);  // swizzled read slot
  const int aoff = (wr * 64 + lo) * 32 + hs * 8;
  const int boff = (wc * 64 + lo) * 32 + hs * 8;

  const int nt = K >> 5;
  int c0 = 0, c1 = 4096, c2 = 8192;  // rotating buffer bases (elems)

  // prologue: stage tiles 0 and 1; wait tile 0 only
  gload16(Ag0, As + c0 + sb);       gload16(Ag1, As + c0 + sb + 2048);
  gload16(Bg0, Bs + c0 + sb);       gload16(Bg1, Bs + c0 + sb + 2048);
  gload16(Ag0 + 32, As + c1 + sb);  gload16(Ag1 + 32, As + c1 + sb + 2048);
  gload16(Bg0 + 32, Bs + c1 + sb);  gload16(Bg1 + 32, Bs + c1 + sb + 2048);
  bar_v4();

  for (int t = 0; t < nt; ++t) {
    if (t + 2 < nt) {  // prefetch tile t+2 into the free buffer
      const int k0 = (t + 2) << 5;
      gload16(Ag0 + k0, As + c2 + sb);
      gload16(Ag1 + k0, As + c2 + sb + 2048);
      gload16(Bg0 + k0, Bs + c2 + sb);
      gload16(Bg1 + k0, Bs + c2 + sb + 2048);
    }
    short8 af[4], bf[4];
#pragma unroll
    for (int m = 0; m < 4; ++m)
      af[m] = *(const short8_a*)(As + c0 + aoff + m * 512);
#pragma unroll
    for (int n = 0; n < 4; ++n)
      bf[n] = *(const short8_a*)(Bs + c0 + boff + n * 512);
    __builtin_amdgcn_s_setprio(1);
#pragma unroll
    for (int m = 0; m < 4; ++m)
#pragma unroll
      for (int n = 0; n < 4; ++n) mfma_b(acc[m][n], af[m], bf[n]);
    __builtin_amdgcn_s_setprio(0);
    if (t + 2 < nt) bar_v4();  // tile t+1 landed; t+2 still in flight
    else bar_v0();             // tail: drain
    const int tmp = c0; c0 = c1; c1 = c2; c2 = tmp;
  }
  guard8(&acc[0][0]);  // MFMA->VALU hazard fence before epilogue acc reads
  guard8(&acc[2][0]);

  if constexpr (EPI == 0) {
#pragma unroll
    for (int m = 0; m < 4; ++m) {
      const int row0 = m0 + wr * 64 + m * 16 + hi * 4;
#pragma unroll
      for (int n = 0; n < 4; ++n) {
        const int col = n0 + wc * 64 + n * 16 + lo;
#pragma unroll
        for (int r = 0; r < 4; ++r)
          C[(long)(row0 + r) * N + col] = acc[m][n][r];
      }
    }
  } else {
    if (n0 < 5120) {  // Q or K columns: RoPE (pair partner lives in lane lo^1)
      const bool isQ = (n0 < 4096);
#pragma unroll
      for (int m = 0; m < 4; ++m) {
        const int row0 = m0 + wr * 64 + m * 16 + hi * 4;
#pragma unroll
        for (int n = 0; n < 4; ++n) {
          const int c = n0 + wc * 64 + n * 16 + lo;
          const int j0 = (c & 127) >> 1;
          const bool even = ((c & 1) == 0);
#pragma unroll
          for (int r = 0; r < 4; ++r) {
            float own = acc[m][n][r];
            float part = __shfl_xor(own, 1);
            const int s_ = row0 + r;
            const float cv = cost[s_ * 64 + j0];
            const float sv = sint[s_ * 64 + j0];
            float res = even ? (own * cv - part * sv) : (part * sv + own * cv);
            if (isQ)
              Qb[(long)s_ * 4096 + c] = f2b(res * QK_SCALE);
            else
              Kb[(long)s_ * 1024 + (c - 4096)] = f2b(res);
          }
        }
      }
    } else {  // V columns: transposed bf16 store Vt[c][s], 4 rows packed
#pragma unroll
      for (int m = 0; m < 4; ++m) {
        const int row0 = m0 + wr * 64 + m * 16 + hi * 4;
#pragma unroll
        for (int n = 0; n < 4; ++n) {
          const int vc = n0 - 5120 + wc * 64 + n * 16 + lo;
          u16x4 pk;
#pragma unroll
          for (int r = 0; r < 4; ++r) pk[r] = f2b(acc[m][n][r]);
          *(u16x4_a*)(Vt + (long)vc * 2048 + row0) = pk;
        }
      }
    }
  }
}

// ---------------- causal GQA flash attention (MFMA, cluster-guarded) ----------------
// Qb: [2048][4096] bf16 (pre-scaled), Kb: [2048][1024] bf16,
// Vt: [1024][2048] bf16 (d-major), Ab out: [2048][4096] bf16.
#define KLD 136  // 128 + 8 pad (elems)
#define VLD 72   // 64 + 8 pad (elems)
__global__ __launch_bounds__(256, 2)
void k_attn(const u16* __restrict__ Qb, const u16* __restrict__ Kb,
            const u16* __restrict__ Vt, u16* __restrict__ Ab) {
  __shared__ u16 Ks[64 * KLD];
  __shared__ u16 Vs[128 * VLD];
  __shared__ u16 Ps[4 * 16 * VLD];

  const int tid = threadIdx.x;
  const int w = tid >> 6, lane = tid & 63;
  const int hi = lane >> 4, lo = lane & 15;
  // heavy-first: qt descending in launch order (block work ~ qt+1)
  const int qt = 31 - (blockIdx.x >> 5);
  const int h = blockIdx.x & 31;
  const int hkv = h >> 2;
  const int q0 = qt * 64;
  const int qrow = q0 + w * 16 + lo;  // score-q for this lane (D col = lo)

  short8 qf[4];
#pragma unroll
  for (int c = 0; c < 4; ++c)
    qf[c] = *(const short8_a*)(Qb + (long)qrow * 4096 + h * 128 + c * 32 + hi * 8);

  f32x4 o[8] = {};
  float m_run = -1e30f, l_run = 0.f;
  u16* Pw = Ps + w * (16 * VLD);

  const int ntiles = qt + 1;
  for (int t = 0; t < ntiles; ++t) {
    const int kv0 = t * 64;
    __syncthreads();
    // stage K tile [64][128] -> padded LDS
#pragma unroll
    for (int r = 0; r < 4; ++r) {
      int i = r * 256 + tid;
      int key = i >> 4, d8 = (i & 15) * 8;
      short8 v = *(const short8_a*)(Kb + (long)(kv0 + key) * 1024 + hkv * 128 + d8);
      *(short8_a*)(Ks + key * KLD + d8) = v;
    }
    // stage V^T tile [128][64] -> padded LDS
#pragma unroll
    for (int r = 0; r < 4; ++r) {
      int i = r * 256 + tid;
      int dd = i >> 3, k8 = (i & 7) * 8;
      short8 v = *(const short8_a*)(Vt + (long)hkv * 262144 + (long)dd * 2048 + kv0 + k8);
      *(short8_a*)(Vs + dd * VLD + k8) = v;
    }
    __syncthreads();

    // swapped QK^T: D[key = hi*4+r (+16*kt)][q = lo]
    f32x4 sc[4] = {};
#pragma unroll
    for (int c = 0; c < 4; ++c) {
#pragma unroll
      for (int kt = 0; kt < 4; ++kt) {
        short8 kf = *(const short8_a*)(Ks + (kt * 16 + lo) * KLD + c * 32 + hi * 8);
        mfma_b(sc[kt], kf, qf[c]);
      }
    }
    guard4(sc[0], sc[1], sc[2], sc[3]);  // MFMA->VALU hazard fence

    if (t == ntiles - 1) {  // diagonal tile: causal mask
#pragma unroll
      for (int kt = 0; kt < 4; ++kt)
#pragma unroll
        for (int r = 0; r < 4; ++r) {
          int key = kv0 + kt * 16 + hi * 4 + r;
          if (key > qrow) sc[kt][r] = -1e30f;
        }
    }
    // online softmax (row q = lo; lanes hi=0..3 hold 16 keys each)
    float tmax = -1e30f;
#pragma unroll
    for (int kt = 0; kt < 4; ++kt)
#pragma unroll
      for (int r = 0; r < 4; ++r) tmax = fmaxf(tmax, sc[kt][r]);
    tmax = fmaxf(tmax, __shfl_xor(tmax, 16));
    tmax = fmaxf(tmax, __shfl_xor(tmax, 32));
    float m_new = fmaxf(m_run, tmax);
    float scale = __expf(m_run - m_new);
    float psum = 0.f;
    float p[16];
#pragma unroll
    for (int kt = 0; kt < 4; ++kt)
#pragma unroll
      for (int r = 0; r < 4; ++r) {
        float pv = __expf(sc[kt][r] - m_new);
        p[kt * 4 + r] = pv;
        psum += pv;
      }
    psum += __shfl_xor(psum, 16);
    psum += __shfl_xor(psum, 32);
    l_run = l_run * scale + psum;
    m_run = m_new;
    // rescale O (PV-D rows q = hi*4+r need the scale of score-lane lo = hi*4+r)
    float srow[4];
#pragma unroll
    for (int r = 0; r < 4; ++r) srow[r] = __shfl(scale, hi * 4 + r);
#pragma unroll
    for (int n = 0; n < 8; ++n)
#pragma unroll
      for (int r = 0; r < 4; ++r) o[n][r] *= srow[r];
    // P -> LDS (bf16), row q = lo, 64 keys padded to VLD
#pragma unroll
    for (int kt = 0; kt < 4; ++kt) {
      unsigned p01 = (unsigned)f2b(p[kt * 4]) | ((unsigned)f2b(p[kt * 4 + 1]) << 16);
      unsigned p23 = (unsigned)f2b(p[kt * 4 + 2]) | ((unsigned)f2b(p[kt * 4 + 3]) << 16);
      *(uint_a*)(Pw + lo * VLD + kt * 16 + hi * 4) = p01;
      *(uint_a*)(Pw + lo * VLD + kt * 16 + hi * 4 + 2) = p23;
    }
    __syncthreads();  // order P-store -> P-read (cross-lane via LDS)
    // PV: D[q = hi*4+r][d = n*16+lo] += P[q][k] * V[k][d]
#pragma unroll
    for (int c = 0; c < 2; ++c) {
      short8 pf = *(const short8_a*)(Pw + lo * VLD + c * 32 + hi * 8);
#pragma unroll
      for (int n = 0; n < 8; ++n) {
        short8 vf = *(const short8_a*)(Vs + (n * 16 + lo) * VLD + c * 32 + hi * 8);
        mfma_b(o[n], pf, vf);
      }
    }
  }
  guard8(o);  // MFMA->VALU hazard fence before epilogue reads of o

  // finalize: divide by row sums, write bf16
  float inv = 1.0f / l_run;
  float irow[4];
#pragma unroll
  for (int r = 0; r < 4; ++r) irow[r] = __shfl(inv, hi * 4 + r);
#pragma unroll
  for (int n = 0; n < 8; ++n)
#pragma unroll
    for (int r = 0; r < 4; ++r) {
      int q = q0 + w * 16 + hi * 4 + r;
      Ab[(long)q * 4096 + h * 128 + n * 16 + lo] = f2b(o[n][r] * irow[r]);
    }
}

// ---------------- host ----------------
extern "C" void kernel_launch(void* const* d_in, const int* in_sizes, int n_in,
                              void* d_out, int out_size, void* d_ws, size_t ws_size,
                              hipStream_t stream) {
  const float* x = (const float*)d_in[0];
  const float* wq = (const float*)d_in[1];
  const float* wk = (const float*)d_in[2];
  const float* wv = (const float*)d_in[3];
  const float* wo = (const float*)d_in[4];
  float* out = (float*)d_out;
  char* ws = (char*)d_ws;

  size_t off = 0;
  u16* xb = (u16*)(ws + off); off += 16777216;     // x 2048x4096 bf16
  u16* wB = (u16*)(ws + off); off += 50331648;     // [wq;wk;wv] 6144x4096 bf16
  u16* wob = (u16*)(ws + off); off += 33554432;    // wo 4096x4096 bf16
  u16* Qb = (u16*)(ws + off); off += 16777216;     // 2048x4096 bf16 (roped, scaled)
  u16* Kb = (u16*)(ws + off); off += 4194304;      // 2048x1024 bf16 (roped)
  u16* Vtb = (u16*)(ws + off); off += 4194304;     // 1024x2048 bf16 (transposed)
  float* cost = (float*)(ws + off); off += 524288; // 2048x64 f32
  float* sint = (float*)(ws + off); off += 524288;
  u16* Ab = (u16*)(ws + off); off += 16777216;     // attn out 2048x4096 bf16

  // merged casts + rope table (wB rows: wq 0..4095, wk 4096..5119, wv 5120..6143)
  k_prep<<<49664, 256, 0, stream>>>(x, wq, wk, wv, wo, xb, wB, wob, cost, sint);

  // fused QKV projection: GEMM + RoPE/scale/transpose epilogue
  k_gemm_t<1><<<768, 256, 0, stream>>>(xb, wB, nullptr, 2048, 6144, 4096,
                                       cost, sint, Qb, Kb, Vtb);

  // attention
  k_attn<<<1024, 256, 0, stream>>>(Qb, Kb, Vtb, Ab);

  // output projection
  k_gemm_t<0><<<512, 256, 0, stream>>>(Ab, wob, out, 2048, 4096, 4096,
                                       nullptr, nullptr, nullptr, nullptr, nullptr);
}

// Round 8
// 371.226 us; speedup vs baseline: 10.7924x; 1.0190x over previous
//
#include <hip/hip_runtime.h>

typedef unsigned short u16;
typedef short short8 __attribute__((ext_vector_type(8)));
typedef float f32x4 __attribute__((ext_vector_type(4)));
typedef unsigned short u16x4 __attribute__((ext_vector_type(4)));

typedef short8 short8_a __attribute__((may_alias));
typedef f32x4 f32x4_a __attribute__((may_alias));
typedef u16x4 u16x4_a __attribute__((may_alias));
typedef unsigned int uint_a __attribute__((may_alias));

__device__ __forceinline__ u16 f2b(float f) {
  unsigned u = __float_as_uint(f);
  u += 0x7FFFu + ((u >> 16) & 1u);
  return (u16)(u >> 16);
}

// Nop-free MFMA: safe when D is next read >16cy away or behind a guard below.
__device__ __forceinline__ void mfma_b(f32x4& d, short8 a, short8 b) {
  asm("v_mfma_f32_16x16x32_bf16 %0, %1, %2, %0" : "+v"(d) : "v"(a), "v"(b));
}

// MFMA->VALU hazard guards, register-tied (dataflow-ordered; rule #18 safe).
__device__ __forceinline__ void guard4(f32x4& a, f32x4& b, f32x4& c, f32x4& d) {
  asm volatile("s_nop 7\n\ts_nop 7" : "+v"(a), "+v"(b), "+v"(c), "+v"(d));
}
__device__ __forceinline__ void guard8(f32x4* o) {
  asm volatile("s_nop 7\n\ts_nop 7"
               : "+v"(o[0]), "+v"(o[1]), "+v"(o[2]), "+v"(o[3]),
                 "+v"(o[4]), "+v"(o[5]), "+v"(o[6]), "+v"(o[7]));
}

__device__ __forceinline__ void gload16(const void* g, void* l) {
  __builtin_amdgcn_global_load_lds((__attribute__((address_space(1))) void*)(g),
                                   (__attribute__((address_space(3))) void*)(l),
                                   16, 0, 0);
}

__device__ __forceinline__ void bar_v0() {
  asm volatile("s_waitcnt vmcnt(0)\n\ts_barrier" ::: "memory");
}
__device__ __forceinline__ void bar_v4() {
  asm volatile("s_waitcnt vmcnt(4)\n\ts_barrier" ::: "memory");
}

// ---------------- merged prep: all fp32->bf16 casts + rope table ----------------
__global__ __launch_bounds__(256)
void k_prep(const float* __restrict__ x, const float* __restrict__ wq,
            const float* __restrict__ wk, const float* __restrict__ wv,
            const float* __restrict__ wo, u16* __restrict__ xb,
            u16* __restrict__ wB, u16* __restrict__ wob,
            float* __restrict__ cost, float* __restrict__ sint) {
  const long i = (long)blockIdx.x * 256 + threadIdx.x;
  const float* src;
  u16* dst;
  long j;
  if (i < 6291456) {
    if (i < 2097152) { src = x; dst = xb; j = i; }
    else { src = wq; dst = wB; j = i - 2097152; }
  } else if (i < 8388608) {
    if (i < 7340032) { src = wk; dst = wB + 16777216; j = i - 6291456; }
    else { src = wv; dst = wB + 20971520; j = i - 7340032; }
  } else if (i < 12582912) {
    src = wo; dst = wob; j = i - 8388608;
  } else {
    long ti = i - 12582912;  // [0, 131072): rope table
    int s = (int)(ti >> 6), jj = (int)(ti & 63);
    float freq = powf(500000.0f, -(float)jj * (1.0f / 64.0f));
    float a = (float)s * freq;
    float sv, cv;
    sincosf(a, &sv, &cv);
    cost[ti] = cv;
    sint[ti] = sv;
    return;
  }
  f32x4 v = ((const f32x4_a*)src)[j];
  u16x4 o;
  o[0] = f2b(v[0]); o[1] = f2b(v[1]); o[2] = f2b(v[2]); o[3] = f2b(v[3]);
  ((u16x4_a*)dst)[j] = o;
}

// ================= 256^2 8-wave QKV GEMM with fused RoPE epilogue =================
// C[2048][6144] = xb[2048][4096] * wB[6144][4096]^T, tiles 256x256, BK=64,
// 2 LDS buffers (128 KB dynamic), race-free phase schedule (see analysis),
// LDS XOR-swizzle slot^=(row&7) applied stage-source + read (rule #21).
// Epilogue: cols [0,4096) RoPE*scale->Qb; [4096,5120) RoPE->Kb; [5120,6144)
// transpose->Vt.
#define QK_SCALE 0.08838834764831845f
__global__ __launch_bounds__(512, 2)
void k_gemm8(const u16* __restrict__ A, const u16* __restrict__ B,
             const float* __restrict__ cost, const float* __restrict__ sint,
             u16* __restrict__ Qb, u16* __restrict__ Kb, u16* __restrict__ Vt) {
  extern __shared__ u16 lds[];  // A: [2][256][64] @0, B: [2][256][64] @32768
  const int K = 4096;
  const int tid = threadIdx.x;
  const int w = tid >> 6, lane = tid & 63;
  const int hi = lane >> 4, lo = lane & 15;
  const int wr = w >> 2, wc = w & 3;  // 2M x 4N wave grid
  int bid = blockIdx.x;               // 192 = 8 XCD-groups x 24
  bid = (bid & 7) * 24 + (bid >> 3);
  const int tm = bid / 24, tn = bid - (bid / 24) * 24;
  const int m0 = tm << 8, n0 = tn << 8;

  // staging geometry: thread -> dest row (tid>>3), dest slot (tid&7);
  // source k-slot = destslot ^ (row&7)  (inverse of the read swizzle)
  const int kx = (((tid & 7) ^ ((tid >> 3) & 7)) << 3);  // elems
  const int r3 = tid >> 3;                               // 0..63

  f32x4 acc[8][4] = {};
  short8 afr[4][2], bfr[4][2];

  // frag read offsets (elems): row*64 + ((ks*4+hi)^(lo&7))*8
  const int sA0 = (wr * 128 + lo) * 64;  // + fm*16*64
  const int sB0 = (wc * 64 + lo) * 64;   // + fn*16*64
  const int sl0 = ((0 * 4 + hi) ^ (lo & 7)) * 8;
  const int sl1 = ((1 * 4 + hi) ^ (lo & 7)) * 8;

#define STAGE_A(sbuf, h, kt)                                                    \
  {                                                                             \
    _Pragma("unroll") for (int l = 0; l < 2; ++l) {                             \
      gload16(A + (long)(m0 + (h)*128 + l * 64 + r3) * K + (kt)*64 + kx,        \
              lds + (sbuf)*16384 + ((h)*128 + l * 64 + w * 8) * 64);            \
    }                                                                           \
  }
#define STAGE_B(sbuf, h, kt)                                                    \
  {                                                                             \
    _Pragma("unroll") for (int l = 0; l < 2; ++l) {                             \
      gload16(B + (long)(n0 + (h)*128 + l * 64 + r3) * K + (kt)*64 + kx,        \
              lds + 32768 + (sbuf)*16384 + ((h)*128 + l * 64 + w * 8) * 64);    \
    }                                                                           \
  }

  // prologue: stage tile 0 -> buf0, drain once
  STAGE_A(0, 0, 0); STAGE_A(0, 1, 0);
  STAGE_B(0, 0, 0); STAGE_B(0, 1, 0);
  bar_v0();

  const int NI = K >> 7;  // 32 iters, 2 K-tiles each
#define HALF_ITER(buf, stile, sbuf, dostage)                                    \
  {                                                                             \
    const u16* Ab_ = lds + (buf)*16384;                                         \
    const u16* Bb_ = lds + 32768 + (buf)*16384;                                 \
    if (dostage) { STAGE_A(sbuf, 0, stile); STAGE_A(sbuf, 1, stile); }          \
    _Pragma("unroll") for (int fn = 0; fn < 4; ++fn) {                          \
      bfr[fn][0] = *(const short8_a*)(Bb_ + sB0 + fn * 1024 + sl0);             \
      bfr[fn][1] = *(const short8_a*)(Bb_ + sB0 + fn * 1024 + sl1);             \
    }                                                                           \
    _Pragma("unroll") for (int fm = 0; fm < 4; ++fm) {                          \
      afr[fm][0] = *(const short8_a*)(Ab_ + sA0 + fm * 1024 + sl0);             \
      afr[fm][1] = *(const short8_a*)(Ab_ + sA0 + fm * 1024 + sl1);             \
    }                                                                           \
    __builtin_amdgcn_s_setprio(1);                                              \
    _Pragma("unroll") for (int fm = 0; fm < 4; ++fm)                            \
      _Pragma("unroll") for (int fn = 0; fn < 4; ++fn) {                        \
        mfma_b(acc[fm][fn], afr[fm][0], bfr[fn][0]);                            \
        mfma_b(acc[fm][fn], afr[fm][1], bfr[fn][1]);                            \
      }                                                                         \
    __builtin_amdgcn_s_setprio(0);                                              \
    if (dostage) { STAGE_B(sbuf, 0, stile); STAGE_B(sbuf, 1, stile); }          \
    _Pragma("unroll") for (int fm = 0; fm < 4; ++fm) {                          \
      afr[fm][0] = *(const short8_a*)(Ab_ + sA0 + (fm + 4) * 1024 + sl0);       \
      afr[fm][1] = *(const short8_a*)(Ab_ + sA0 + (fm + 4) * 1024 + sl1);       \
    }                                                                           \
    __builtin_amdgcn_s_setprio(1);                                              \
    _Pragma("unroll") for (int fm = 0; fm < 4; ++fm)                            \
      _Pragma("unroll") for (int fn = 0; fn < 4; ++fn) {                        \
        mfma_b(acc[fm + 4][fn], afr[fm][0], bfr[fn][0]);                        \
        mfma_b(acc[fm + 4][fn], afr[fm][1], bfr[fn][1]);                        \
      }                                                                         \
    __builtin_amdgcn_s_setprio(0);                                              \
    bar_v0();                                                                   \
  }

  for (int it = 0; it < NI; ++it) {
    // K-tile 2it in buf0; stage tile 2it+1 -> buf1 (buf1 freed at prev barrier)
    HALF_ITER(0, 2 * it + 1, 1, true);
    // K-tile 2it+1 in buf1; stage tile 2it+2 -> buf0 (freed at mid barrier)
    HALF_ITER(1, 2 * it + 2, 0, (it + 1 < NI));
  }

  guard8(&acc[0][0]); guard8(&acc[2][0]); guard8(&acc[4][0]); guard8(&acc[6][0]);

  // fused epilogue (segment is uniform per block: n0 is 256-aligned)
  if (n0 < 5120) {  // Q or K: RoPE (pair partner in lane lo^1)
    const bool isQ = (n0 < 4096);
#pragma unroll
    for (int fm = 0; fm < 8; ++fm) {
      const int row0 = m0 + wr * 128 + fm * 16 + hi * 4;
#pragma unroll
      for (int fn = 0; fn < 4; ++fn) {
        const int c = n0 + wc * 64 + fn * 16 + lo;
        const int j0 = (c & 127) >> 1;
        const bool even = ((c & 1) == 0);
#pragma unroll
        for (int r = 0; r < 4; ++r) {
          float own = acc[fm][fn][r];
          float part = __shfl_xor(own, 1);
          const int s_ = row0 + r;
          const float cv = cost[s_ * 64 + j0];
          const float sv = sint[s_ * 64 + j0];
          float res = even ? (own * cv - part * sv) : (part * sv + own * cv);
          if (isQ)
            Qb[(long)s_ * 4096 + c] = f2b(res * QK_SCALE);
          else
            Kb[(long)s_ * 1024 + (c - 4096)] = f2b(res);
        }
      }
    }
  } else {  // V: transposed store Vt[c][s], 4 rows packed
#pragma unroll
    for (int fm = 0; fm < 8; ++fm) {
      const int row0 = m0 + wr * 128 + fm * 16 + hi * 4;
#pragma unroll
      for (int fn = 0; fn < 4; ++fn) {
        const int vc = n0 - 5120 + wc * 64 + fn * 16 + lo;
        u16x4 pk;
#pragma unroll
        for (int r = 0; r < 4; ++r) pk[r] = f2b(acc[fm][fn][r]);
        *(u16x4_a*)(Vt + (long)vc * 2048 + row0) = pk;
      }
    }
  }
#undef HALF_ITER
#undef STAGE_A
#undef STAGE_B
}

// ---- 128^2 bf16 GEMM (verified R7 structure): out-projection ----
template <int EPI>
__global__ __launch_bounds__(256, 2)
void k_gemm_t(const u16* __restrict__ A, const u16* __restrict__ B,
              float* __restrict__ C, int M, int N, int K) {
  __shared__ u16 As[12288];
  __shared__ u16 Bs[12288];
  const int tid = threadIdx.x;
  const int w = tid >> 6, lane = tid & 63;
  const int hi = lane >> 4, lo = lane & 15;
  const int nwg = gridDim.x;
  int bid = blockIdx.x;
  if ((nwg & 7) == 0) bid = (bid & 7) * (nwg >> 3) + (bid >> 3);
  const int ntn = N >> 7;
  const int tm = bid / ntn, tn = bid - tm * ntn;
  const int m0 = tm << 7, n0 = tn << 7;
  const int wr = w >> 1, wc = w & 1;

  const int rowl = w * 16 + (lane >> 2);
  const int ks = (((lane & 3) ^ ((lane >> 3) & 3)) << 3);
  const u16* Ag0 = A + (long)(m0 + rowl) * K + ks;
  const u16* Ag1 = A + (long)(m0 + 64 + rowl) * K + ks;
  const u16* Bg0 = B + (long)(n0 + rowl) * K + ks;
  const u16* Bg1 = B + (long)(n0 + 64 + rowl) * K + ks;
  const int sb = w * 512;

  f32x4 acc[4][4] = {};
  const int hs = hi ^ ((lo >> 1) & 3);
  const int aoff = (wr * 64 + lo) * 32 + hs * 8;
  const int boff = (wc * 64 + lo) * 32 + hs * 8;

  const int nt = K >> 5;
  int c0 = 0, c1 = 4096, c2 = 8192;

  gload16(Ag0, As + c0 + sb);       gload16(Ag1, As + c0 + sb + 2048);
  gload16(Bg0, Bs + c0 + sb);       gload16(Bg1, Bs + c0 + sb + 2048);
  gload16(Ag0 + 32, As + c1 + sb);  gload16(Ag1 + 32, As + c1 + sb + 2048);
  gload16(Bg0 + 32, Bs + c1 + sb);  gload16(Bg1 + 32, Bs + c1 + sb + 2048);
  bar_v4();

  for (int t = 0; t < nt; ++t) {
    if (t + 2 < nt) {
      const int k0 = (t + 2) << 5;
      gload16(Ag0 + k0, As + c2 + sb);
      gload16(Ag1 + k0, As + c2 + sb + 2048);
      gload16(Bg0 + k0, Bs + c2 + sb);
      gload16(Bg1 + k0, Bs + c2 + sb + 2048);
    }
    short8 af[4], bf[4];
#pragma unroll
    for (int m = 0; m < 4; ++m)
      af[m] = *(const short8_a*)(As + c0 + aoff + m * 512);
#pragma unroll
    for (int n = 0; n < 4; ++n)
      bf[n] = *(const short8_a*)(Bs + c0 + boff + n * 512);
    __builtin_amdgcn_s_setprio(1);
#pragma unroll
    for (int m = 0; m < 4; ++m)
#pragma unroll
      for (int n = 0; n < 4; ++n) mfma_b(acc[m][n], af[m], bf[n]);
    __builtin_amdgcn_s_setprio(0);
    if (t + 2 < nt) bar_v4();
    else bar_v0();
    const int tmp = c0; c0 = c1; c1 = c2; c2 = tmp;
  }
  guard8(&acc[0][0]);
  guard8(&acc[2][0]);

#pragma unroll
  for (int m = 0; m < 4; ++m) {
    const int row0 = m0 + wr * 64 + m * 16 + hi * 4;
#pragma unroll
    for (int n = 0; n < 4; ++n) {
      const int col = n0 + wc * 64 + n * 16 + lo;
#pragma unroll
      for (int r = 0; r < 4; ++r)
        C[(long)(row0 + r) * N + col] = acc[m][n][r];
    }
  }
}

// ---------------- causal GQA flash attention (MFMA, cluster-guarded) ----------------
#define KLD 136
#define VLD 72
__global__ __launch_bounds__(256, 2)
void k_attn(const u16* __restrict__ Qb, const u16* __restrict__ Kb,
            const u16* __restrict__ Vt, u16* __restrict__ Ab) {
  __shared__ u16 Ks[64 * KLD];
  __shared__ u16 Vs[128 * VLD];
  __shared__ u16 Ps[4 * 16 * VLD];

  const int tid = threadIdx.x;
  const int w = tid >> 6, lane = tid & 63;
  const int hi = lane >> 4, lo = lane & 15;
  const int qt = 31 - (blockIdx.x >> 5);
  const int h = blockIdx.x & 31;
  const int hkv = h >> 2;
  const int q0 = qt * 64;
  const int qrow = q0 + w * 16 + lo;

  short8 qf[4];
#pragma unroll
  for (int c = 0; c < 4; ++c)
    qf[c] = *(const short8_a*)(Qb + (long)qrow * 4096 + h * 128 + c * 32 + hi * 8);

  f32x4 o[8] = {};
  float m_run = -1e30f, l_run = 0.f;
  u16* Pw = Ps + w * (16 * VLD);

  const int ntiles = qt + 1;
  for (int t = 0; t < ntiles; ++t) {
    const int kv0 = t * 64;
    __syncthreads();
#pragma unroll
    for (int r = 0; r < 4; ++r) {
      int i = r * 256 + tid;
      int key = i >> 4, d8 = (i & 15) * 8;
      short8 v = *(const short8_a*)(Kb + (long)(kv0 + key) * 1024 + hkv * 128 + d8);
      *(short8_a*)(Ks + key * KLD + d8) = v;
    }
#pragma unroll
    for (int r = 0; r < 4; ++r) {
      int i = r * 256 + tid;
      int dd = i >> 3, k8 = (i & 7) * 8;
      short8 v = *(const short8_a*)(Vt + (long)hkv * 262144 + (long)dd * 2048 + kv0 + k8);
      *(short8_a*)(Vs + dd * VLD + k8) = v;
    }
    __syncthreads();

    f32x4 sc[4] = {};
#pragma unroll
    for (int c = 0; c < 4; ++c) {
#pragma unroll
      for (int kt = 0; kt < 4; ++kt) {
        short8 kf = *(const short8_a*)(Ks + (kt * 16 + lo) * KLD + c * 32 + hi * 8);
        mfma_b(sc[kt], kf, qf[c]);
      }
    }
    guard4(sc[0], sc[1], sc[2], sc[3]);

    if (t == ntiles - 1) {
#pragma unroll
      for (int kt = 0; kt < 4; ++kt)
#pragma unroll
        for (int r = 0; r < 4; ++r) {
          int key = kv0 + kt * 16 + hi * 4 + r;
          if (key > qrow) sc[kt][r] = -1e30f;
        }
    }
    float tmax = -1e30f;
#pragma unroll
    for (int kt = 0; kt < 4; ++kt)
#pragma unroll
      for (int r = 0; r < 4; ++r) tmax = fmaxf(tmax, sc[kt][r]);
    tmax = fmaxf(tmax, __shfl_xor(tmax, 16));
    tmax = fmaxf(tmax, __shfl_xor(tmax, 32));
    float m_new = fmaxf(m_run, tmax);
    float scale = __expf(m_run - m_new);
    float psum = 0.f;
    float p[16];
#pragma unroll
    for (int kt = 0; kt < 4; ++kt)
#pragma unroll
      for (int r = 0; r < 4; ++r) {
        float pv = __expf(sc[kt][r] - m_new);
        p[kt * 4 + r] = pv;
        psum += pv;
      }
    psum += __shfl_xor(psum, 16);
    psum += __shfl_xor(psum, 32);
    l_run = l_run * scale + psum;
    m_run = m_new;
    float srow[4];
#pragma unroll
    for (int r = 0; r < 4; ++r) srow[r] = __shfl(scale, hi * 4 + r);
#pragma unroll
    for (int n = 0; n < 8; ++n)
#pragma unroll
      for (int r = 0; r < 4; ++r) o[n][r] *= srow[r];
#pragma unroll
    for (int kt = 0; kt < 4; ++kt) {
      unsigned p01 = (unsigned)f2b(p[kt * 4]) | ((unsigned)f2b(p[kt * 4 + 1]) << 16);
      unsigned p23 = (unsigned)f2b(p[kt * 4 + 2]) | ((unsigned)f2b(p[kt * 4 + 3]) << 16);
      *(uint_a*)(Pw + lo * VLD + kt * 16 + hi * 4) = p01;
      *(uint_a*)(Pw + lo * VLD + kt * 16 + hi * 4 + 2) = p23;
    }
    __syncthreads();
#pragma unroll
    for (int c = 0; c < 2; ++c) {
      short8 pf = *(const short8_a*)(Pw + lo * VLD + c * 32 + hi * 8);
#pragma unroll
      for (int n = 0; n < 8; ++n) {
        short8 vf = *(const short8_a*)(Vs + (n * 16 + lo) * VLD + c * 32 + hi * 8);
        mfma_b(o[n], pf, vf);
      }
    }
  }
  guard8(o);

  float inv = 1.0f / l_run;
  float irow[4];
#pragma unroll
  for (int r = 0; r < 4; ++r) irow[r] = __shfl(inv, hi * 4 + r);
#pragma unroll
  for (int n = 0; n < 8; ++n)
#pragma unroll
    for (int r = 0; r < 4; ++r) {
      int q = q0 + w * 16 + hi * 4 + r;
      Ab[(long)q * 4096 + h * 128 + n * 16 + lo] = f2b(o[n][r] * irow[r]);
    }
}

// ---------------- host ----------------
extern "C" void kernel_launch(void* const* d_in, const int* in_sizes, int n_in,
                              void* d_out, int out_size, void* d_ws, size_t ws_size,
                              hipStream_t stream) {
  const float* x = (const float*)d_in[0];
  const float* wq = (const float*)d_in[1];
  const float* wk = (const float*)d_in[2];
  const float* wv = (const float*)d_in[3];
  const float* wo = (const float*)d_in[4];
  float* out = (float*)d_out;
  char* ws = (char*)d_ws;

  size_t off = 0;
  u16* xb = (u16*)(ws + off); off += 16777216;
  u16* wB = (u16*)(ws + off); off += 50331648;
  u16* wob = (u16*)(ws + off); off += 33554432;
  u16* Qb = (u16*)(ws + off); off += 16777216;
  u16* Kb = (u16*)(ws + off); off += 4194304;
  u16* Vtb = (u16*)(ws + off); off += 4194304;
  float* cost = (float*)(ws + off); off += 524288;
  float* sint = (float*)(ws + off); off += 524288;
  u16* Ab = (u16*)(ws + off); off += 16777216;

  static bool attr_set = false;
  if (!attr_set) {
    hipFuncSetAttribute((const void*)k_gemm8,
                        hipFuncAttributeMaxDynamicSharedMemorySize, 131072);
    attr_set = true;
  }

  k_prep<<<49664, 256, 0, stream>>>(x, wq, wk, wv, wo, xb, wB, wob, cost, sint);

  // fused QKV projection: 256^2 8-wave pipelined GEMM + RoPE/transpose epilogue
  k_gemm8<<<192, 512, 131072, stream>>>(xb, wB, cost, sint, Qb, Kb, Vtb);

  // attention
  k_attn<<<1024, 256, 0, stream>>>(Qb, Kb, Vtb, Ab);

  // output projection (verified 128^2 structure)
  k_gemm_t<0><<<512, 256, 0, stream>>>(Ab, wob, out, 2048, 4096, 4096);
}

// Round 11
// 351.272 us; speedup vs baseline: 11.4055x; 1.0568x over previous
//
#include <hip/hip_runtime.h>

typedef unsigned short u16;
typedef short short8 __attribute__((ext_vector_type(8)));
typedef float f32x4 __attribute__((ext_vector_type(4)));
typedef unsigned short u16x4 __attribute__((ext_vector_type(4)));

typedef short8 short8_a __attribute__((may_alias));
typedef f32x4 f32x4_a __attribute__((may_alias));
typedef u16x4 u16x4_a __attribute__((may_alias));
typedef unsigned int uint_a __attribute__((may_alias));

__device__ __forceinline__ u16 f2b(float f) {
  unsigned u = __float_as_uint(f);
  u += 0x7FFFu + ((u >> 16) & 1u);
  return (u16)(u >> 16);
}

// Nop-free MFMA: safe when D is next read >16cy away or behind a guard below.
__device__ __forceinline__ void mfma_b(f32x4& d, short8 a, short8 b) {
  asm("v_mfma_f32_16x16x32_bf16 %0, %1, %2, %0" : "+v"(d) : "v"(a), "v"(b));
}

// MFMA->VALU hazard guards, register-tied (dataflow-ordered; rule #18 safe).
__device__ __forceinline__ void guard4(f32x4& a, f32x4& b, f32x4& c, f32x4& d) {
  asm volatile("s_nop 7\n\ts_nop 7" : "+v"(a), "+v"(b), "+v"(c), "+v"(d));
}
__device__ __forceinline__ void guard8(f32x4* o) {
  asm volatile("s_nop 7\n\ts_nop 7"
               : "+v"(o[0]), "+v"(o[1]), "+v"(o[2]), "+v"(o[3]),
                 "+v"(o[4]), "+v"(o[5]), "+v"(o[6]), "+v"(o[7]));
}

__device__ __forceinline__ void gload16(const void* g, void* l) {
  __builtin_amdgcn_global_load_lds((__attribute__((address_space(1))) void*)(g),
                                   (__attribute__((address_space(3))) void*)(l),
                                   16, 0, 0);
}

__device__ __forceinline__ void bar_v0() {
  asm volatile("s_waitcnt vmcnt(0)\n\ts_barrier" ::: "memory");
}
__device__ __forceinline__ void bar_v3() {
  asm volatile("s_waitcnt vmcnt(3)\n\ts_barrier" ::: "memory");
}

// ---------------- merged prep: all fp32->bf16 casts + rope table (R8-verified) ----
__global__ __launch_bounds__(256)
void k_prep(const float* __restrict__ x, const float* __restrict__ wq,
            const float* __restrict__ wk, const float* __restrict__ wv,
            const float* __restrict__ wo, u16* __restrict__ xb,
            u16* __restrict__ wB, u16* __restrict__ wob,
            float* __restrict__ cost, float* __restrict__ sint) {
  const long i = (long)blockIdx.x * 256 + threadIdx.x;
  const float* src;
  u16* dst;
  long j;
  if (i < 6291456) {
    if (i < 2097152) { src = x; dst = xb; j = i; }
    else { src = wq; dst = wB; j = i - 2097152; }
  } else if (i < 8388608) {
    if (i < 7340032) { src = wk; dst = wB + 16777216; j = i - 6291456; }
    else { src = wv; dst = wB + 20971520; j = i - 7340032; }
  } else if (i < 12582912) {
    src = wo; dst = wob; j = i - 8388608;
  } else {
    long ti = i - 12582912;  // [0, 131072): rope table
    int s = (int)(ti >> 6), jj = (int)(ti & 63);
    float freq = powf(500000.0f, -(float)jj * (1.0f / 64.0f));
    float a = (float)s * freq;
    float sv, cv;
    sincosf(a, &sv, &cv);
    cost[ti] = cv;
    sint[ti] = sv;
    return;
  }
  f32x4 v = ((const f32x4_a*)src)[j];
  u16x4 o;
  o[0] = f2b(v[0]); o[1] = f2b(v[1]); o[2] = f2b(v[2]); o[3] = f2b(v[3]);
  ((u16x4_a*)dst)[j] = o;
}

// ================= 256^2 8-wave QKV GEMM with fused RoPE epilogue (R8-verified) ====
#define QK_SCALE 0.08838834764831845f
__global__ __launch_bounds__(512, 2)
void k_gemm8(const u16* __restrict__ A, const u16* __restrict__ B,
             const float* __restrict__ cost, const float* __restrict__ sint,
             u16* __restrict__ Qb, u16* __restrict__ Kb, u16* __restrict__ Vt) {
  extern __shared__ u16 lds[];  // A: [2][256][64] @0, B: [2][256][64] @32768
  const int K = 4096;
  const int tid = threadIdx.x;
  const int w = tid >> 6, lane = tid & 63;
  const int hi = lane >> 4, lo = lane & 15;
  const int wr = w >> 2, wc = w & 3;  // 2M x 4N wave grid
  int bid = blockIdx.x;               // 192 = 8 XCD-groups x 24
  bid = (bid & 7) * 24 + (bid >> 3);
  const int tm = bid / 24, tn = bid - (bid / 24) * 24;
  const int m0 = tm << 8, n0 = tn << 8;

  const int kx = (((tid & 7) ^ ((tid >> 3) & 7)) << 3);  // elems
  const int r3 = tid >> 3;                               // 0..63

  f32x4 acc[8][4] = {};
  short8 afr[4][2], bfr[4][2];

  const int sA0 = (wr * 128 + lo) * 64;  // + fm*16*64
  const int sB0 = (wc * 64 + lo) * 64;   // + fn*16*64
  const int sl0 = ((0 * 4 + hi) ^ (lo & 7)) * 8;
  const int sl1 = ((1 * 4 + hi) ^ (lo & 7)) * 8;

#define STAGE_A(sbuf, h, kt)                                                    \
  {                                                                             \
    _Pragma("unroll") for (int l = 0; l < 2; ++l) {                             \
      gload16(A + (long)(m0 + (h)*128 + l * 64 + r3) * K + (kt)*64 + kx,        \
              lds + (sbuf)*16384 + ((h)*128 + l * 64 + w * 8) * 64);            \
    }                                                                           \
  }
#define STAGE_B(sbuf, h, kt)                                                    \
  {                                                                             \
    _Pragma("unroll") for (int l = 0; l < 2; ++l) {                             \
      gload16(B + (long)(n0 + (h)*128 + l * 64 + r3) * K + (kt)*64 + kx,        \
              lds + 32768 + (sbuf)*16384 + ((h)*128 + l * 64 + w * 8) * 64);    \
    }                                                                           \
  }

  // prologue: stage tile 0 -> buf0, drain once
  STAGE_A(0, 0, 0); STAGE_A(0, 1, 0);
  STAGE_B(0, 0, 0); STAGE_B(0, 1, 0);
  bar_v0();

  const int NI = K >> 7;  // 32 iters, 2 K-tiles each
#define HALF_ITER(buf, stile, sbuf, dostage)                                    \
  {                                                                             \
    const u16* Ab_ = lds + (buf)*16384;                                         \
    const u16* Bb_ = lds + 32768 + (buf)*16384;                                 \
    if (dostage) { STAGE_A(sbuf, 0, stile); STAGE_A(sbuf, 1, stile); }          \
    _Pragma("unroll") for (int fn = 0; fn < 4; ++fn) {                          \
      bfr[fn][0] = *(const short8_a*)(Bb_ + sB0 + fn * 1024 + sl0);             \
      bfr[fn][1] = *(const short8_a*)(Bb_ + sB0 + fn * 1024 + sl1);             \
    }                                                                           \
    _Pragma("unroll") for (int fm = 0; fm < 4; ++fm) {                          \
      afr[fm][0] = *(const short8_a*)(Ab_ + sA0 + fm * 1024 + sl0);             \
      afr[fm][1] = *(const short8_a*)(Ab_ + sA0 + fm * 1024 + sl1);             \
    }                                                                           \
    __builtin_amdgcn_s_setprio(1);                                              \
    _Pragma("unroll") for (int fm = 0; fm < 4; ++fm)                            \
      _Pragma("unroll") for (int fn = 0; fn < 4; ++fn) {                        \
        mfma_b(acc[fm][fn], afr[fm][0], bfr[fn][0]);                            \
        mfma_b(acc[fm][fn], afr[fm][1], bfr[fn][1]);                            \
      }                                                                         \
    __builtin_amdgcn_s_setprio(0);                                              \
    if (dostage) { STAGE_B(sbuf, 0, stile); STAGE_B(sbuf, 1, stile); }          \
    _Pragma("unroll") for (int fm = 0; fm < 4; ++fm) {                          \
      afr[fm][0] = *(const short8_a*)(Ab_ + sA0 + (fm + 4) * 1024 + sl0);       \
      afr[fm][1] = *(const short8_a*)(Ab_ + sA0 + (fm + 4) * 1024 + sl1);       \
    }                                                                           \
    __builtin_amdgcn_s_setprio(1);                                              \
    _Pragma("unroll") for (int fm = 0; fm < 4; ++fm)                            \
      _Pragma("unroll") for (int fn = 0; fn < 4; ++fn) {                        \
        mfma_b(acc[fm + 4][fn], afr[fm][0], bfr[fn][0]);                        \
        mfma_b(acc[fm + 4][fn], afr[fm][1], bfr[fn][1]);                        \
      }                                                                         \
    __builtin_amdgcn_s_setprio(0);                                              \
    bar_v0();                                                                   \
  }

  for (int it = 0; it < NI; ++it) {
    HALF_ITER(0, 2 * it + 1, 1, true);
    HALF_ITER(1, 2 * it + 2, 0, (it + 1 < NI));
  }

  guard8(&acc[0][0]); guard8(&acc[2][0]); guard8(&acc[4][0]); guard8(&acc[6][0]);

  if (n0 < 5120) {  // Q or K: RoPE (pair partner in lane lo^1)
    const bool isQ = (n0 < 4096);
#pragma unroll
    for (int fm = 0; fm < 8; ++fm) {
      const int row0 = m0 + wr * 128 + fm * 16 + hi * 4;
#pragma unroll
      for (int fn = 0; fn < 4; ++fn) {
        const int c = n0 + wc * 64 + fn * 16 + lo;
        const int j0 = (c & 127) >> 1;
        const bool even = ((c & 1) == 0);
#pragma unroll
        for (int r = 0; r < 4; ++r) {
          float own = acc[fm][fn][r];
          float part = __shfl_xor(own, 1);
          const int s_ = row0 + r;
          const float cv = cost[s_ * 64 + j0];
          const float sv = sint[s_ * 64 + j0];
          float res = even ? (own * cv - part * sv) : (part * sv + own * cv);
          if (isQ)
            Qb[(long)s_ * 4096 + c] = f2b(res * QK_SCALE);
          else
            Kb[(long)s_ * 1024 + (c - 4096)] = f2b(res);
        }
      }
    }
  } else {  // V: transposed store Vt[c][s], 4 rows packed
#pragma unroll
    for (int fm = 0; fm < 8; ++fm) {
      const int row0 = m0 + wr * 128 + fm * 16 + hi * 4;
#pragma unroll
      for (int fn = 0; fn < 4; ++fn) {
        const int vc = n0 - 5120 + wc * 64 + fn * 16 + lo;
        u16x4 pk;
#pragma unroll
        for (int r = 0; r < 4; ++r) pk[r] = f2b(acc[fm][fn][r]);
        *(u16x4_a*)(Vt + (long)vc * 2048 + row0) = pk;
      }
    }
  }
#undef HALF_ITER
#undef STAGE_A
#undef STAGE_B
}

// ---- NEW: 128x256-tile 8-wave out-projection (widened from verified k_gemm_t) ----
// C[2048][4096] = A[2048][4096] * B[4096][4096]^T. BK=32, triple-buffered,
// counted vmcnt(3). Swizzle involution keyed on (row>>1)&3, both sides:
// stage source slot = (tid&3)^((tid>>3)&3)  [row = tid>>2 => (row>>1)&3 = (tid>>3)&3]
// read slot        = hi ^ ((lo>>1)&3)       [row = ..+lo  => (row>>1)&3 = (lo>>1)&3]
__global__ __launch_bounds__(512, 2)
void k_gemm_t2(const u16* __restrict__ A, const u16* __restrict__ B,
               float* __restrict__ C) {
  extern __shared__ u16 lds2[];
  u16* As = lds2;           // 3 bufs x 4096 elems (128 x 32)
  u16* Bs = lds2 + 12288;   // 3 bufs x 8192 elems (256 x 32)
  const int K = 4096, N = 4096;
  const int tid = threadIdx.x;
  const int w = tid >> 6, lane = tid & 63;
  const int hi = lane >> 4, lo = lane & 15;
  const int wr = w >> 2, wc = w & 3;  // 2M x 4N waves -> per-wave 64x64
  int bid = blockIdx.x;               // 256 = 16(tm) x 16(tn)
  bid = (bid & 7) * 32 + (bid >> 3);  // XCD swizzle (bijective, 256%8==0)
  const int tm = bid >> 4, tn = bid & 15;
  const int m0 = tm << 7, n0 = tn << 8;

  const int r2 = tid >> 2;  // 0..127
  const int ks = (((tid & 3) ^ ((tid >> 3) & 3)) << 3);
  const u16* Ag = A + (long)(m0 + r2) * K + ks;
  const u16* Bg0 = B + (long)(n0 + r2) * K + ks;
  const u16* Bg1 = B + (long)(n0 + 128 + r2) * K + ks;
  const int sb = w * 512;  // dest elems = tid*8 -> wave-uniform base + lane*16B

  f32x4 acc[4][4] = {};
  const int hs = hi ^ ((lo >> 1) & 3);
  const int aoff = (wr * 64 + lo) * 32 + hs * 8;
  const int boff = (wc * 64 + lo) * 32 + hs * 8;

  const int nt = K >> 5;  // 128
  int i0 = 0, i1 = 1, i2 = 2;

#define STG2(kt, bi)                                      \
  {                                                       \
    gload16(Ag + (kt)*32, As + (bi)*4096 + sb);           \
    gload16(Bg0 + (kt)*32, Bs + (bi)*8192 + sb);          \
    gload16(Bg1 + (kt)*32, Bs + (bi)*8192 + 4096 + sb);   \
  }

  STG2(0, 0);
  STG2(1, 1);
  bar_v3();  // tile 0 landed; tile 1's 3 loads still in flight

  for (int t = 0; t < nt; ++t) {
    if (t + 2 < nt) STG2(t + 2, i2);
    short8 af[4], bf[4];
#pragma unroll
    for (int m = 0; m < 4; ++m)
      af[m] = *(const short8_a*)(As + i0 * 4096 + aoff + m * 512);
#pragma unroll
    for (int n = 0; n < 4; ++n)
      bf[n] = *(const short8_a*)(Bs + i0 * 8192 + boff + n * 512);
    __builtin_amdgcn_s_setprio(1);
#pragma unroll
    for (int m = 0; m < 4; ++m)
#pragma unroll
      for (int n = 0; n < 4; ++n) mfma_b(acc[m][n], af[m], bf[n]);
    __builtin_amdgcn_s_setprio(0);
    if (t + 2 < nt) bar_v3();  // tile t+1 landed; t+2's 3 loads in flight
    else bar_v0();             // tail drain
    const int tmp = i0; i0 = i1; i1 = i2; i2 = tmp;
  }
#undef STG2
  guard8(&acc[0][0]);
  guard8(&acc[2][0]);

#pragma unroll
  for (int m = 0; m < 4; ++m) {
    const int row0 = m0 + wr * 64 + m * 16 + hi * 4;
#pragma unroll
    for (int n = 0; n < 4; ++n) {
      const int col = n0 + wc * 64 + n * 16 + lo;
#pragma unroll
      for (int r = 0; r < 4; ++r)
        C[(long)(row0 + r) * N + col] = acc[m][n][r];
    }
  }
}

// ---------------- causal GQA flash attention (verified) ----------------
#define KLD 136
#define VLD 72
__global__ __launch_bounds__(256, 2)
void k_attn(const u16* __restrict__ Qb, const u16* __restrict__ Kb,
            const u16* __restrict__ Vt, u16* __restrict__ Ab) {
  __shared__ u16 Ks[64 * KLD];
  __shared__ u16 Vs[128 * VLD];
  __shared__ u16 Ps[4 * 16 * VLD];

  const int tid = threadIdx.x;
  const int w = tid >> 6, lane = tid & 63;
  const int hi = lane >> 4, lo = lane & 15;
  const int qt = 31 - (blockIdx.x >> 5);
  const int h = blockIdx.x & 31;
  const int hkv = h >> 2;
  const int q0 = qt * 64;
  const int qrow = q0 + w * 16 + lo;

  short8 qf[4];
#pragma unroll
  for (int c = 0; c < 4; ++c)
    qf[c] = *(const short8_a*)(Qb + (long)qrow * 4096 + h * 128 + c * 32 + hi * 8);

  f32x4 o[8] = {};
  float m_run = -1e30f, l_run = 0.f;
  u16* Pw = Ps + w * (16 * VLD);

  const int ntiles = qt + 1;
  for (int t = 0; t < ntiles; ++t) {
    const int kv0 = t * 64;
    __syncthreads();
#pragma unroll
    for (int r = 0; r < 4; ++r) {
      int i = r * 256 + tid;
      int key = i >> 4, d8 = (i & 15) * 8;
      short8 v = *(const short8_a*)(Kb + (long)(kv0 + key) * 1024 + hkv * 128 + d8);
      *(short8_a*)(Ks + key * KLD + d8) = v;
    }
#pragma unroll
    for (int r = 0; r < 4; ++r) {
      int i = r * 256 + tid;
      int dd = i >> 3, k8 = (i & 7) * 8;
      short8 v = *(const short8_a*)(Vt + (long)hkv * 262144 + (long)dd * 2048 + kv0 + k8);
      *(short8_a*)(Vs + dd * VLD + k8) = v;
    }
    __syncthreads();

    f32x4 sc[4] = {};
#pragma unroll
    for (int c = 0; c < 4; ++c) {
#pragma unroll
      for (int kt = 0; kt < 4; ++kt) {
        short8 kf = *(const short8_a*)(Ks + (kt * 16 + lo) * KLD + c * 32 + hi * 8);
        mfma_b(sc[kt], kf, qf[c]);
      }
    }
    guard4(sc[0], sc[1], sc[2], sc[3]);

    if (t == ntiles - 1) {
#pragma unroll
      for (int kt = 0; kt < 4; ++kt)
#pragma unroll
        for (int r = 0; r < 4; ++r) {
          int key = kv0 + kt * 16 + hi * 4 + r;
          if (key > qrow) sc[kt][r] = -1e30f;
        }
    }
    float tmax = -1e30f;
#pragma unroll
    for (int kt = 0; kt < 4; ++kt)
#pragma unroll
      for (int r = 0; r < 4; ++r) tmax = fmaxf(tmax, sc[kt][r]);
    tmax = fmaxf(tmax, __shfl_xor(tmax, 16));
    tmax = fmaxf(tmax, __shfl_xor(tmax, 32));
    float m_new = fmaxf(m_run, tmax);
    float scale = __expf(m_run - m_new);
    float psum = 0.f;
    float p[16];
#pragma unroll
    for (int kt = 0; kt < 4; ++kt)
#pragma unroll
      for (int r = 0; r < 4; ++r) {
        float pv = __expf(sc[kt][r] - m_new);
        p[kt * 4 + r] = pv;
        psum += pv;
      }
    psum += __shfl_xor(psum, 16);
    psum += __shfl_xor(psum, 32);
    l_run = l_run * scale + psum;
    m_run = m_new;
    float srow[4];
#pragma unroll
    for (int r = 0; r < 4; ++r) srow[r] = __shfl(scale, hi * 4 + r);
#pragma unroll
    for (int n = 0; n < 8; ++n)
#pragma unroll
      for (int r = 0; r < 4; ++r) o[n][r] *= srow[r];
#pragma unroll
    for (int kt = 0; kt < 4; ++kt) {
      unsigned p01 = (unsigned)f2b(p[kt * 4]) | ((unsigned)f2b(p[kt * 4 + 1]) << 16);
      unsigned p23 = (unsigned)f2b(p[kt * 4 + 2]) | ((unsigned)f2b(p[kt * 4 + 3]) << 16);
      *(uint_a*)(Pw + lo * VLD + kt * 16 + hi * 4) = p01;
      *(uint_a*)(Pw + lo * VLD + kt * 16 + hi * 4 + 2) = p23;
    }
    __syncthreads();
#pragma unroll
    for (int c = 0; c < 2; ++c) {
      short8 pf = *(const short8_a*)(Pw + lo * VLD + c * 32 + hi * 8);
#pragma unroll
      for (int n = 0; n < 8; ++n) {
        short8 vf = *(const short8_a*)(Vs + (n * 16 + lo) * VLD + c * 32 + hi * 8);
        mfma_b(o[n], pf, vf);
      }
    }
  }
  guard8(o);

  float inv = 1.0f / l_run;
  float irow[4];
#pragma unroll
  for (int r = 0; r < 4; ++r) irow[r] = __shfl(inv, hi * 4 + r);
#pragma unroll
  for (int n = 0; n < 8; ++n)
#pragma unroll
    for (int r = 0; r < 4; ++r) {
      int q = q0 + w * 16 + hi * 4 + r;
      Ab[(long)q * 4096 + h * 128 + n * 16 + lo] = f2b(o[n][r] * irow[r]);
    }
}

// ---------------- host ----------------
extern "C" void kernel_launch(void* const* d_in, const int* in_sizes, int n_in,
                              void* d_out, int out_size, void* d_ws, size_t ws_size,
                              hipStream_t stream) {
  const float* x = (const float*)d_in[0];
  const float* wq = (const float*)d_in[1];
  const float* wk = (const float*)d_in[2];
  const float* wv = (const float*)d_in[3];
  const float* wo = (const float*)d_in[4];
  float* out = (float*)d_out;
  char* ws = (char*)d_ws;

  size_t off = 0;
  u16* xb = (u16*)(ws + off); off += 16777216;     // x 2048x4096 bf16
  u16* wB = (u16*)(ws + off); off += 50331648;     // [wq;wk;wv] 6144x4096 bf16
  u16* wob = (u16*)(ws + off); off += 33554432;    // wo bf16
  u16* Qb = (u16*)(ws + off); off += 16777216;     // roped, scaled Q
  u16* Kb = (u16*)(ws + off); off += 4194304;      // roped K
  u16* Vtb = (u16*)(ws + off); off += 4194304;     // transposed V
  float* cost = (float*)(ws + off); off += 524288; // 2048x64
  float* sint = (float*)(ws + off); off += 524288;
  u16* Ab = (u16*)(ws + off); off += 16777216;     // attn out

  static bool attr_set = false;
  if (!attr_set) {
    hipFuncSetAttribute((const void*)k_gemm8,
                        hipFuncAttributeMaxDynamicSharedMemorySize, 131072);
    hipFuncSetAttribute((const void*)k_gemm_t2,
                        hipFuncAttributeMaxDynamicSharedMemorySize, 73728);
    attr_set = true;
  }

  // prep: all weight/x casts + rope table (R8-verified)
  k_prep<<<49664, 256, 0, stream>>>(x, wq, wk, wv, wo, xb, wB, wob, cost, sint);

  // fused QKV projection (R8-verified k_gemm8)
  k_gemm8<<<192, 512, 131072, stream>>>(xb, wB, cost, sint, Qb, Kb, Vtb);

  // attention (verified)
  k_attn<<<1024, 256, 0, stream>>>(Qb, Kb, Vtb, Ab);

  // output projection: NEW 128x256-tile 8-wave variant
  k_gemm_t2<<<256, 512, 73728, stream>>>(Ab, wob, out);
}